// Round 5
// baseline (118.145 us; speedup 1.0000x reference)
//
#include <hip/hip_runtime.h>
#include <hip/hip_bf16.h>
#include <stdint.h>

// Shapes: B=8, T=2048, E=1024, H=64
// wei[t][s] = k[t]·q[s] * 0.125 (k plays "query"), causal s<=t.
// 0.125*log2(e) folded into Wk so softmax uses exp2 directly.

typedef __attribute__((ext_vector_type(4))) float f32x4;
typedef __attribute__((ext_vector_type(4))) short s16x4;
typedef __attribute__((ext_vector_type(8))) short s16x8;
typedef __attribute__((ext_vector_type(2))) unsigned int u32x2;
typedef __attribute__((ext_vector_type(4))) unsigned int u32x4;

__device__ __forceinline__ unsigned bf16pack(float a, float b){
    unsigned ua = __builtin_bit_cast(unsigned, a);
    unsigned ub = __builtin_bit_cast(unsigned, b);
    return ((ua + 0x8000u) >> 16) | ((ub + 0x8000u) & 0xffff0000u);
}
__device__ __forceinline__ unsigned short bf16one(float a){
    return (unsigned short)((__builtin_bit_cast(unsigned, a) + 0x8000u) >> 16);
}

// ---------------- W prep: WT[192][1024] bf16 (rows 0..63 k-scaled, 64..127 q, 128..191 v) ----------
__global__ __launch_bounds__(256) void wprep_kernel(const float* __restrict__ Wk,
                                                    const float* __restrict__ Wq,
                                                    const float* __restrict__ Wv,
                                                    unsigned short* __restrict__ WT){
    __shared__ float lw[1024][8];
    int w = blockIdx.x, n0 = blockIdx.y * 8, tid = threadIdx.x;
    const float* src = (w == 0) ? Wk : (w == 1) ? Wq : Wv;
    float scale = (w == 0) ? 0.18033688011112042f : 1.0f;  // 0.125 * log2(e)
    for (int it = 0; it < 8; ++it){
        int idx = it * 256 + tid;
        int k = idx >> 1, half = idx & 1;
        f32x4 v = *(const f32x4*)(src + k * 64 + n0 + half * 4);
        *(f32x4*)&lw[k][half * 4] = v;
    }
    __syncthreads();
    int n = tid >> 5, kc = (tid & 31) * 32;
    unsigned short* dst = WT + (size_t)((w * 64 + n0 + n) * 1024 + kc);
    #pragma unroll
    for (int c = 0; c < 4; c++){
        s16x8 v;
        #pragma unroll
        for (int e = 0; e < 8; e++)
            v[e] = (short)bf16one(lw[kc + c * 8 + e][n] * scale);
        *(s16x8*)(dst + c * 8) = v;
    }
}

// ---------------- Projections v5: 512 blocks x 512 thr (8 waves), 32-row tiles ----------------
// wave w: mh = w>>2 (16-row m-frag), nsub = w&3 (3 n-tiles). 2 blocks/CU = 16 waves/CU.
// x staged fp32->bf16 into swizzled LDS [32][64] dbuf; B (WT) direct from L2; loads pinned.
__global__ __launch_bounds__(512, 4) void proj_kernel(const float* __restrict__ x,
                                                      const unsigned short* __restrict__ WT,
                                                      unsigned short* __restrict__ kb,
                                                      unsigned short* __restrict__ qb,
                                                      unsigned short* __restrict__ vP){
    __shared__ unsigned short smem[32 * 200];  // dbuf x-tiles [0..2047],[2048..4095]; out-tile [32][200]
    int tid = threadIdx.x; int l = tid & 63;
    int w = tid >> 6;
    int lr = l & 15, lg = l >> 4;
    int mh = w >> 2, nsub = w & 3;
    int row0 = blockIdx.x * 32;
    int b = row0 >> 11, t0 = row0 & 2047;

    // staging map: thread -> (srow 0..31, chunk 0..7, half); swizzle chunk ^= srow&7 (write side)
    int srow = tid >> 4, sub = tid & 15;
    int chunk = sub >> 1, half = sub & 1;
    const float* sg = x + (size_t)(row0 + srow) * 1024 + chunk * 8 + half * 4;
    unsigned short* swr = smem + srow * 64 + ((chunk ^ (srow & 7)) * 8) + half * 4;

    // A ds-read addrs (buf0): row = mh*16+lr, chunk = (kc*4+lg)^(row&7)
    const unsigned short* ard[2];
    int ar = mh * 16 + lr;
    #pragma unroll
    for (int kc = 0; kc < 2; kc++)
        ard[kc] = smem + ar * 64 + (((kc * 4 + lg) ^ (ar & 7)) * 8);

    // B global base pointers (3 n-tiles per wave)
    const unsigned short* bp[3];
    #pragma unroll
    for (int nn = 0; nn < 3; nn++)
        bp[nn] = WT + (size_t)((nsub * 3 + nn) * 16 + lr) * 1024 + lg * 8;

    f32x4 acc[3] = {};

    // prologue: stage k0=0 into buf0
    f32x4 xa = *(const f32x4*)(sg);
    {
        u32x2 pk;
        pk[0] = bf16pack(xa[0], xa[1]); pk[1] = bf16pack(xa[2], xa[3]);
        *(u32x2*)swr = pk;
    }
    int cur = 0;
    for (int k0 = 0; k0 < 1024; k0 += 64){
        __syncthreads();
        // B loads for this step
        s16x8 bf[3][2];
        #pragma unroll
        for (int nn = 0; nn < 3; nn++){
            bf[nn][0] = *(const s16x8*)(bp[nn] + k0);
            bf[nn][1] = *(const s16x8*)(bp[nn] + k0 + 32);
        }
        // x load for next step (clamped, unconditional -> no UB)
        int kn = (k0 + 64 < 1024) ? (k0 + 64) : 960;
        xa = *(const f32x4*)(sg + kn);
        // A fragments from LDS (buffer cur)
        s16x8 af[2];
        #pragma unroll
        for (int kc = 0; kc < 2; kc++)
            af[kc] = *(const s16x8*)(ard[kc] + cur * 2048);
        // pin: nothing above sinks below this point
        __builtin_amdgcn_sched_barrier(0);
        #pragma unroll
        for (int nn = 0; nn < 3; nn++){
            acc[nn] = __builtin_amdgcn_mfma_f32_16x16x32_bf16(af[0], bf[nn][0], acc[nn], 0, 0, 0);
            acc[nn] = __builtin_amdgcn_mfma_f32_16x16x32_bf16(af[1], bf[nn][1], acc[nn], 0, 0, 0);
        }
        // convert + stage-write next buf (last iter redundant; overwritten after barrier)
        {
            u32x2 pk;
            pk[0] = bf16pack(xa[0], xa[1]); pk[1] = bf16pack(xa[2], xa[3]);
            *(u32x2*)(swr + (cur ^ 1) * 2048) = pk;
        }
        cur ^= 1;
    }
    __syncthreads();
    // epilogue: acc -> out tile [32][200] bf16 (cols 0..63 k, 64..127 q, 128..191 v)
    #pragma unroll
    for (int nn = 0; nn < 3; nn++){
        int col = (nsub * 3 + nn) * 16 + lr;
        int row = mh * 16 + lg * 4;
        #pragma unroll
        for (int r = 0; r < 4; r++)
            smem[(row + r) * 200 + col] = bf16one(acc[nn][r]);
    }
    __syncthreads();
    {
        // k|q rows: 32 rows x 128 cols, 16B per thread
        int r2 = tid >> 4, c2 = (tid & 15) * 8;
        const unsigned short* srowp = smem + r2 * 200 + c2;
        unsigned short* dst = (c2 < 64)
            ? kb + (size_t)(b * 2048 + t0 + r2) * 64 + c2
            : qb + (size_t)(b * 2048 + t0 + r2) * 64 + (c2 - 64);
        *(s16x8*)(dst) = *(const s16x8*)(srowp);
        if (tid < 256){
            // vP permuted store: slot jj (0..31) holds t-local sl = ((jj&3)|((jj>>3)<<2)) + 16*((jj>>2)&1)
            int h = tid >> 2, q3 = tid & 3;
            s16x8 vv;
            #pragma unroll
            for (int e = 0; e < 8; e++){
                int jj = q3 * 8 + e;
                int bb = (jj >> 2) & 1;
                int aa = (jj & 3) | ((jj >> 3) << 2);
                int sl = aa + 16 * bb;
                vv[e] = smem[sl * 200 + 128 + h];
            }
            *(s16x8*)(vP + (size_t)(b * 64 + h) * 2048 + t0 + q3 * 8) = vv;
        }
    }
}

// ---------------- Flash attention v5: pinned loads; 1024 blocks x 4 waves; strip split ------------
__global__ __launch_bounds__(256, 3) void attn_kernel(const unsigned short* __restrict__ kb,
                                                      const unsigned short* __restrict__ qb,
                                                      const unsigned short* __restrict__ vP,
                                                      float* __restrict__ out){
    __shared__ float sacc[4][16][72];
    __shared__ float sml[4][16][2];
    int tid = threadIdx.x; int l = tid & 63; int strip = tid >> 6;
    int lr = l & 15, lg = l >> 4;
    int b = blockIdx.y;
    int j = 127 - blockIdx.x;  // heavy tiles first
    int t0 = j * 16;
    const unsigned short* fqp = kb + (size_t)(b * 2048 + t0 + lr) * 64 + lg * 8;
    s16x8 fq0 = *(const s16x8*)(fqp);
    s16x8 fq1 = *(const s16x8*)(fqp + 32);
    const unsigned short* qbb = qb + (size_t)b * 2048 * 64;
    const unsigned short* vbb = vP + (size_t)b * 64 * 2048;
    f32x4 acc[4] = {};
    float mrun = -3.0e38f, lrun = 0.0f;
    int dj = j >> 2;  // diagonal 64-chunk index
    for (int idx = strip; idx <= dj; idx += 4){
        int s0 = idx * 64;
        // k + v fragment loads all issue here; sched_barrier pins them above the MFMAs,
        // so QK waits only on k (in-order vmcnt) and v stays in flight through softmax.
        s16x8 fk[4][2];
        #pragma unroll
        for (int n = 0; n < 4; n++){
            const unsigned short* kp = qbb + (size_t)(s0 + n * 16 + lr) * 64 + lg * 8;
            fk[n][0] = *(const s16x8*)(kp);
            fk[n][1] = *(const s16x8*)(kp + 32);
        }
        s16x8 fvp[4][2];
        #pragma unroll
        for (int h16 = 0; h16 < 4; h16++)
            #pragma unroll
            for (int n2 = 0; n2 < 2; n2++)
                fvp[h16][n2] = *(const s16x8*)(vbb + (size_t)(h16 * 16 + lr) * 2048 + s0 + n2 * 32 + lg * 8);
        __builtin_amdgcn_sched_barrier(0);
        // S^T: C[s][t] = sum_d q[s][d]*k[t][d]
        f32x4 Cs[4];
        #pragma unroll
        for (int n = 0; n < 4; n++){
            f32x4 z = {};
            z     = __builtin_amdgcn_mfma_f32_16x16x32_bf16(fk[n][0], fq0, z, 0, 0, 0);
            Cs[n] = __builtin_amdgcn_mfma_f32_16x16x32_bf16(fk[n][1], fq1, z, 0, 0, 0);
        }
        if (idx == dj){  // diagonal chunk
            int tg = t0 + lr;
            #pragma unroll
            for (int n = 0; n < 4; n++){
                int sg = s0 + n * 16 + lg * 4;
                #pragma unroll
                for (int r = 0; r < 4; r++)
                    if (sg + r > tg) Cs[n][r] = -3.0e38f;
            }
        }
        float pm = -3.0e38f;
        #pragma unroll
        for (int n = 0; n < 4; n++)
            #pragma unroll
            for (int r = 0; r < 4; r++) pm = fmaxf(pm, Cs[n][r]);
        pm = fmaxf(pm, __shfl_xor(pm, 16));
        pm = fmaxf(pm, __shfl_xor(pm, 32));
        float mnew = fmaxf(mrun, pm);
        float scl = exp2f(mrun - mnew);
        float p[4][4]; float ps = 0.0f;
        #pragma unroll
        for (int n = 0; n < 4; n++)
            #pragma unroll
            for (int r = 0; r < 4; r++){ float e = exp2f(Cs[n][r] - mnew); p[n][r] = e; ps += e; }
        ps += __shfl_xor(ps, 16);
        ps += __shfl_xor(ps, 32);
        lrun = lrun * scl + ps;
        mrun = mnew;
        #pragma unroll
        for (int h16 = 0; h16 < 4; h16++) acc[h16] *= scl;
        s16x4 pb[4];
        #pragma unroll
        for (int n = 0; n < 4; n++){
            u32x2 t; t[0] = bf16pack(p[n][0], p[n][1]); t[1] = bf16pack(p[n][2], p[n][3]);
            pb[n] = __builtin_bit_cast(s16x4, t);
        }
        // out^T: C[h][t] += sum_s V^T[h][s] * P^T[s][t]
        #pragma unroll
        for (int h16 = 0; h16 < 4; h16++)
            #pragma unroll
            for (int n2 = 0; n2 < 2; n2++){
                s16x4 flo = __builtin_shufflevector(fvp[h16][n2], fvp[h16][n2], 0, 1, 2, 3);
                s16x4 fhi = __builtin_shufflevector(fvp[h16][n2], fvp[h16][n2], 4, 5, 6, 7);
                acc[h16] = __builtin_amdgcn_mfma_f32_16x16x16bf16_1k(flo, pb[n2 * 2],     acc[h16], 0, 0, 0);
                acc[h16] = __builtin_amdgcn_mfma_f32_16x16x16bf16_1k(fhi, pb[n2 * 2 + 1], acc[h16], 0, 0, 0);
            }
    }
    // write partials (empty strips: mrun=-3e38, lrun=0, acc=0 -> zero weight in combine)
    #pragma unroll
    for (int h16 = 0; h16 < 4; h16++)
        #pragma unroll
        for (int r = 0; r < 4; r++)
            sacc[strip][lr][h16 * 16 + lg * 4 + r] = acc[h16][r];
    if (lg == 0){ sml[strip][lr][0] = mrun; sml[strip][lr][1] = lrun; }
    __syncthreads();
    // combine: thread -> (row = tid>>4, colgroup = (tid&15)*4)
    {
        int row = tid >> 4, cg = (tid & 15) * 4;
        float m0 = sml[0][row][0], m1 = sml[1][row][0], m2 = sml[2][row][0], m3 = sml[3][row][0];
        float mg = fmaxf(fmaxf(m0, m1), fmaxf(m2, m3));
        float w0 = exp2f(m0 - mg), w1 = exp2f(m1 - mg);
        float w2 = exp2f(m2 - mg), w3 = exp2f(m3 - mg);
        float lt = sml[0][row][1] * w0 + sml[1][row][1] * w1 + sml[2][row][1] * w2 + sml[3][row][1] * w3;
        float inv = 1.0f / lt;
        f32x4 o = (*(const f32x4*)&sacc[0][row][cg]) * w0;
        o += (*(const f32x4*)&sacc[1][row][cg]) * w1;
        o += (*(const f32x4*)&sacc[2][row][cg]) * w2;
        o += (*(const f32x4*)&sacc[3][row][cg]) * w3;
        o *= inv;
        *(f32x4*)(out + (size_t)(b * 2048 + t0 + row) * 64 + cg) = o;
    }
}

extern "C" void kernel_launch(void* const* d_in, const int* in_sizes, int n_in,
                              void* d_out, int out_size, void* d_ws, size_t ws_size,
                              hipStream_t stream) {
    const float* x  = (const float*)d_in[0];
    const float* Wk = (const float*)d_in[1];
    const float* Wq = (const float*)d_in[2];
    const float* Wv = (const float*)d_in[3];
    float* out = (float*)d_out;
    char* ws = (char*)d_ws;
    if (ws_size < (size_t)7 * 1024 * 1024) return;
    unsigned short* WT = (unsigned short*)(ws);              // 384 KB
    unsigned short* kb = (unsigned short*)(ws + (1u << 20)); // 2 MB (k * 0.125*log2e)
    unsigned short* qb = (unsigned short*)(ws + (3u << 20)); // 2 MB
    unsigned short* vP = (unsigned short*)(ws + (5u << 20)); // 2 MB ([b][h][t32-permuted])
    hipLaunchKernelGGL(wprep_kernel, dim3(3, 8), dim3(256), 0, stream, Wk, Wq, Wv, WT);
    hipLaunchKernelGGL(proj_kernel, dim3(512), dim3(512), 0, stream, x, WT, kb, qb, vP);
    hipLaunchKernelGGL(attn_kernel, dim3(128, 8), dim3(256), 0, stream, kb, qb, vP, out);
}

// Round 7
// 114.660 us; speedup vs baseline: 1.0304x; 1.0304x over previous
//
#include <hip/hip_runtime.h>
#include <hip/hip_bf16.h>
#include <stdint.h>

// Shapes: B=8, T=2048, E=1024, H=64
// wei[t][s] = k[t]·q[s] * 0.125 (k plays "query"), causal s<=t.
// 0.125*log2(e) folded into Wk so softmax uses exp2 directly.

typedef __attribute__((ext_vector_type(4))) float f32x4;
typedef __attribute__((ext_vector_type(4))) short s16x4;
typedef __attribute__((ext_vector_type(8))) short s16x8;
typedef __attribute__((ext_vector_type(2))) unsigned int u32x2;
typedef __attribute__((ext_vector_type(4))) unsigned int u32x4;

__device__ __forceinline__ unsigned bf16pack(float a, float b){
    unsigned ua = __builtin_bit_cast(unsigned, a);
    unsigned ub = __builtin_bit_cast(unsigned, b);
    return ((ua + 0x8000u) >> 16) | ((ub + 0x8000u) & 0xffff0000u);
}
__device__ __forceinline__ unsigned short bf16one(float a){
    return (unsigned short)((__builtin_bit_cast(unsigned, a) + 0x8000u) >> 16);
}

// ---------------- W prep: WT[192][1024] bf16 (rows 0..63 k-scaled, 64..127 q, 128..191 v) ----------
__global__ __launch_bounds__(256) void wprep_kernel(const float* __restrict__ Wk,
                                                    const float* __restrict__ Wq,
                                                    const float* __restrict__ Wv,
                                                    unsigned short* __restrict__ WT){
    __shared__ float lw[1024][8];
    int w = blockIdx.x, n0 = blockIdx.y * 8, tid = threadIdx.x;
    const float* src = (w == 0) ? Wk : (w == 1) ? Wq : Wv;
    float scale = (w == 0) ? 0.18033688011112042f : 1.0f;  // 0.125 * log2(e)
    for (int it = 0; it < 8; ++it){
        int idx = it * 256 + tid;
        int k = idx >> 1, half = idx & 1;
        f32x4 v = *(const f32x4*)(src + k * 64 + n0 + half * 4);
        *(f32x4*)&lw[k][half * 4] = v;
    }
    __syncthreads();
    int n = tid >> 5, kc = (tid & 31) * 32;
    unsigned short* dst = WT + (size_t)((w * 64 + n0 + n) * 1024 + kc);
    #pragma unroll
    for (int c = 0; c < 4; c++){
        s16x8 v;
        #pragma unroll
        for (int e = 0; e < 8; e++)
            v[e] = (short)bf16one(lw[kc + c * 8 + e][n] * scale);
        *(s16x8*)(dst + c * 8) = v;
    }
}

// ---------------- Projections v5 (verbatim, passed r5): 512 blocks x 512 thr, 32-row tiles --------
__global__ __launch_bounds__(512, 4) void proj_kernel(const float* __restrict__ x,
                                                      const unsigned short* __restrict__ WT,
                                                      unsigned short* __restrict__ kb,
                                                      unsigned short* __restrict__ qb,
                                                      unsigned short* __restrict__ vP){
    __shared__ unsigned short smem[32 * 200];  // dbuf x-tiles [0..2047],[2048..4095]; out-tile [32][200]
    int tid = threadIdx.x; int l = tid & 63;
    int w = tid >> 6;
    int lr = l & 15, lg = l >> 4;
    int mh = w >> 2, nsub = w & 3;
    int row0 = blockIdx.x * 32;
    int b = row0 >> 11, t0 = row0 & 2047;

    // staging map: thread -> (srow 0..31, chunk 0..7, half); swizzle chunk ^= srow&7 (write side)
    int srow = tid >> 4, sub = tid & 15;
    int chunk = sub >> 1, half = sub & 1;
    const float* sg = x + (size_t)(row0 + srow) * 1024 + chunk * 8 + half * 4;
    unsigned short* swr = smem + srow * 64 + ((chunk ^ (srow & 7)) * 8) + half * 4;

    // A ds-read addrs (buf0): row = mh*16+lr, chunk = (kc*4+lg)^(row&7)
    const unsigned short* ard[2];
    int ar = mh * 16 + lr;
    #pragma unroll
    for (int kc = 0; kc < 2; kc++)
        ard[kc] = smem + ar * 64 + (((kc * 4 + lg) ^ (ar & 7)) * 8);

    // B global base pointers (3 n-tiles per wave)
    const unsigned short* bp[3];
    #pragma unroll
    for (int nn = 0; nn < 3; nn++)
        bp[nn] = WT + (size_t)((nsub * 3 + nn) * 16 + lr) * 1024 + lg * 8;

    f32x4 acc[3] = {};

    // prologue: stage k0=0 into buf0
    f32x4 xa = *(const f32x4*)(sg);
    {
        u32x2 pk;
        pk[0] = bf16pack(xa[0], xa[1]); pk[1] = bf16pack(xa[2], xa[3]);
        *(u32x2*)swr = pk;
    }
    int cur = 0;
    for (int k0 = 0; k0 < 1024; k0 += 64){
        __syncthreads();
        // B loads for this step
        s16x8 bf[3][2];
        #pragma unroll
        for (int nn = 0; nn < 3; nn++){
            bf[nn][0] = *(const s16x8*)(bp[nn] + k0);
            bf[nn][1] = *(const s16x8*)(bp[nn] + k0 + 32);
        }
        // x load for next step (clamped, unconditional -> no UB)
        int kn = (k0 + 64 < 1024) ? (k0 + 64) : 960;
        xa = *(const f32x4*)(sg + kn);
        // A fragments from LDS (buffer cur)
        s16x8 af[2];
        #pragma unroll
        for (int kc = 0; kc < 2; kc++)
            af[kc] = *(const s16x8*)(ard[kc] + cur * 2048);
        __builtin_amdgcn_sched_barrier(0);
        #pragma unroll
        for (int nn = 0; nn < 3; nn++){
            acc[nn] = __builtin_amdgcn_mfma_f32_16x16x32_bf16(af[0], bf[nn][0], acc[nn], 0, 0, 0);
            acc[nn] = __builtin_amdgcn_mfma_f32_16x16x32_bf16(af[1], bf[nn][1], acc[nn], 0, 0, 0);
        }
        // convert + stage-write next buf (last iter redundant; overwritten after barrier)
        {
            u32x2 pk;
            pk[0] = bf16pack(xa[0], xa[1]); pk[1] = bf16pack(xa[2], xa[3]);
            *(u32x2*)(swr + (cur ^ 1) * 2048) = pk;
        }
        cur ^= 1;
    }
    __syncthreads();
    // epilogue: acc -> out tile [32][200] bf16 (cols 0..63 k, 64..127 q, 128..191 v)
    #pragma unroll
    for (int nn = 0; nn < 3; nn++){
        int col = (nsub * 3 + nn) * 16 + lr;
        int row = mh * 16 + lg * 4;
        #pragma unroll
        for (int r = 0; r < 4; r++)
            smem[(row + r) * 200 + col] = bf16one(acc[nn][r]);
    }
    __syncthreads();
    {
        // k|q rows: 32 rows x 128 cols, 16B per thread
        int r2 = tid >> 4, c2 = (tid & 15) * 8;
        const unsigned short* srowp = smem + r2 * 200 + c2;
        unsigned short* dst = (c2 < 64)
            ? kb + (size_t)(b * 2048 + t0 + r2) * 64 + c2
            : qb + (size_t)(b * 2048 + t0 + r2) * 64 + (c2 - 64);
        *(s16x8*)(dst) = *(const s16x8*)(srowp);
        if (tid < 256){
            // vP permuted store: slot jj (0..31) holds t-local sl = ((jj&3)|((jj>>3)<<2)) + 16*((jj>>2)&1)
            int h = tid >> 2, q3 = tid & 3;
            s16x8 vv;
            #pragma unroll
            for (int e = 0; e < 8; e++){
                int jj = q3 * 8 + e;
                int bb = (jj >> 2) & 1;
                int aa = (jj & 3) | ((jj >> 3) << 2);
                int sl = aa + 16 * bb;
                vv[e] = smem[sl * 200 + 128 + h];
            }
            *(s16x8*)(vP + (size_t)(b * 64 + h) * 2048 + t0 + q3 * 8) = vv;
        }
    }
}

// ---------------- Flash attention v7: 16-s chunks (short latency chain), XCD-pinned ------------
// grid 1024: b = bx&7 (keeps each batch's 768KB kb/qb/vP in one XCD L2), j = 127-(bx>>3).
// 4 waves = 4 s-strips over 16-s chunks; LDS m/l/acc combine.
__global__ __launch_bounds__(256, 3) void attn_kernel(const unsigned short* __restrict__ kb,
                                                      const unsigned short* __restrict__ qb,
                                                      const unsigned short* __restrict__ vP,
                                                      float* __restrict__ out){
    __shared__ float sacc[4][16][72];
    __shared__ float sml[4][16][2];
    int tid = threadIdx.x; int l = tid & 63; int strip = tid >> 6;
    int lr = l & 15, lg = l >> 4;
    int bx = blockIdx.x;
    int b = bx & 7;
    int j = 127 - (bx >> 3);  // heavy tiles first
    int t0 = j * 16;
    const unsigned short* fqp = kb + (size_t)(b * 2048 + t0 + lr) * 64 + lg * 8;
    s16x8 fq0 = *(const s16x8*)(fqp);
    s16x8 fq1 = *(const s16x8*)(fqp + 32);
    const unsigned short* qbb = qb + (size_t)b * 2048 * 64;
    const unsigned short* vbb = vP + (size_t)b * 64 * 2048;
    f32x4 acc[4] = {};
    float mrun = -3.0e38f, lrun = 0.0f;
    // chunk idx covers s in [idx*16, idx*16+15]; diagonal chunk is idx == j.
    for (int idx = strip; idx <= j; idx += 4){
        int s0 = idx * 16;
        // K fragment (one 16-row tile): 2 x 16B
        const unsigned short* kp = qbb + (size_t)(s0 + lr) * 64 + lg * 8;
        s16x8 fk0 = *(const s16x8*)(kp);
        s16x8 fk1 = *(const s16x8*)(kp + 32);
        // V fragments (one 16-s k-slice): 4 x 8B from permuted vP
        int voff = (idx >> 1) * 32 + (idx & 1) * 4 + lg * 8;
        s16x4 fv[4];
        #pragma unroll
        for (int h16 = 0; h16 < 4; h16++)
            fv[h16] = *(const s16x4*)(vbb + (size_t)(h16 * 16 + lr) * 2048 + voff);
        // S^T 16x16: C[s][t] = sum_d q[s][d]*k[t][d]
        f32x4 Cs;
        {
            f32x4 z = {};
            z  = __builtin_amdgcn_mfma_f32_16x16x32_bf16(fk0, fq0, z, 0, 0, 0);
            Cs = __builtin_amdgcn_mfma_f32_16x16x32_bf16(fk1, fq1, z, 0, 0, 0);
        }
        if (idx == j){  // diagonal tile: mask s>t  (s-local lg*4+r, t-local lr)
            #pragma unroll
            for (int r = 0; r < 4; r++)
                if (lg * 4 + r > lr) Cs[r] = -3.0e38f;
        }
        // online softmax over s for column t=lr
        float pm = fmaxf(fmaxf(Cs[0], Cs[1]), fmaxf(Cs[2], Cs[3]));
        pm = fmaxf(pm, __shfl_xor(pm, 16));
        pm = fmaxf(pm, __shfl_xor(pm, 32));
        float mnew = fmaxf(mrun, pm);
        float scl = exp2f(mrun - mnew);
        float p0 = exp2f(Cs[0] - mnew), p1 = exp2f(Cs[1] - mnew);
        float p2 = exp2f(Cs[2] - mnew), p3 = exp2f(Cs[3] - mnew);
        float ps = (p0 + p1) + (p2 + p3);
        ps += __shfl_xor(ps, 16);
        ps += __shfl_xor(ps, 32);
        lrun = lrun * scl + ps;
        mrun = mnew;
        #pragma unroll
        for (int h16 = 0; h16 < 4; h16++) acc[h16] *= scl;
        s16x4 pb;
        {
            u32x2 t; t[0] = bf16pack(p0, p1); t[1] = bf16pack(p2, p3);
            pb = __builtin_bit_cast(s16x4, t);
        }
        // out^T: C[h][t] += V^T[h][s] * P^T[s][t]  (k-dim 16)
        #pragma unroll
        for (int h16 = 0; h16 < 4; h16++)
            acc[h16] = __builtin_amdgcn_mfma_f32_16x16x16bf16_1k(fv[h16], pb, acc[h16], 0, 0, 0);
    }
    // write partials (empty strips: mrun=-3e38, lrun=0, acc=0 -> zero weight in combine)
    #pragma unroll
    for (int h16 = 0; h16 < 4; h16++)
        #pragma unroll
        for (int r = 0; r < 4; r++)
            sacc[strip][lr][h16 * 16 + lg * 4 + r] = acc[h16][r];
    if (lg == 0){ sml[strip][lr][0] = mrun; sml[strip][lr][1] = lrun; }
    __syncthreads();
    // combine: thread -> (row = tid>>4, colgroup = (tid&15)*4)
    {
        int row = tid >> 4, cg = (tid & 15) * 4;
        float m0 = sml[0][row][0], m1 = sml[1][row][0], m2 = sml[2][row][0], m3 = sml[3][row][0];
        float mg = fmaxf(fmaxf(m0, m1), fmaxf(m2, m3));
        float w0 = exp2f(m0 - mg), w1 = exp2f(m1 - mg);
        float w2 = exp2f(m2 - mg), w3 = exp2f(m3 - mg);
        float lt = sml[0][row][1] * w0 + sml[1][row][1] * w1 + sml[2][row][1] * w2 + sml[3][row][1] * w3;
        float inv = 1.0f / lt;
        f32x4 o = (*(const f32x4*)&sacc[0][row][cg]) * w0;
        o += (*(const f32x4*)&sacc[1][row][cg]) * w1;
        o += (*(const f32x4*)&sacc[2][row][cg]) * w2;
        o += (*(const f32x4*)&sacc[3][row][cg]) * w3;
        o *= inv;
        *(f32x4*)(out + (size_t)(b * 2048 + t0 + row) * 64 + cg) = o;
    }
}

extern "C" void kernel_launch(void* const* d_in, const int* in_sizes, int n_in,
                              void* d_out, int out_size, void* d_ws, size_t ws_size,
                              hipStream_t stream) {
    const float* x  = (const float*)d_in[0];
    const float* Wk = (const float*)d_in[1];
    const float* Wq = (const float*)d_in[2];
    const float* Wv = (const float*)d_in[3];
    float* out = (float*)d_out;
    char* ws = (char*)d_ws;
    if (ws_size < (size_t)7 * 1024 * 1024) return;
    unsigned short* WT = (unsigned short*)(ws);              // 384 KB
    unsigned short* kb = (unsigned short*)(ws + (1u << 20)); // 2 MB (k * 0.125*log2e)
    unsigned short* qb = (unsigned short*)(ws + (3u << 20)); // 2 MB
    unsigned short* vP = (unsigned short*)(ws + (5u << 20)); // 2 MB ([b][h][t32-permuted])
    hipLaunchKernelGGL(wprep_kernel, dim3(3, 8), dim3(256), 0, stream, Wk, Wq, Wv, WT);
    hipLaunchKernelGGL(proj_kernel, dim3(512), dim3(512), 0, stream, x, WT, kb, qb, vP);
    hipLaunchKernelGGL(attn_kernel, dim3(1024), dim3(256), 0, stream, kb, qb, vP, out);
}

// Round 8
// 100.787 us; speedup vs baseline: 1.1722x; 1.1377x over previous
//
#include <hip/hip_runtime.h>
#include <hip/hip_bf16.h>
#include <stdint.h>

// Shapes: B=8, T=2048, E=1024, H=64
// wei[t][s] = k[t]·q[s] * 0.125 (k plays "query"), causal s<=t.
// 0.125*log2(e) folded into Wk so softmax uses exp2 directly.

typedef __attribute__((ext_vector_type(4))) float f32x4;
typedef __attribute__((ext_vector_type(4))) short s16x4;
typedef __attribute__((ext_vector_type(8))) short s16x8;
typedef __attribute__((ext_vector_type(2))) unsigned int u32x2;
typedef __attribute__((ext_vector_type(4))) unsigned int u32x4;

__device__ __forceinline__ unsigned bf16pack(float a, float b){
    unsigned ua = __builtin_bit_cast(unsigned, a);
    unsigned ub = __builtin_bit_cast(unsigned, b);
    return ((ua + 0x8000u) >> 16) | ((ub + 0x8000u) & 0xffff0000u);
}
__device__ __forceinline__ unsigned short bf16one(float a){
    return (unsigned short)((__builtin_bit_cast(unsigned, a) + 0x8000u) >> 16);
}
// async global->LDS DMA, 16B per lane; LDS dest = uniform base + lane*16 (linear)
__device__ __forceinline__ void gload16(const unsigned short* g, unsigned short* l){
    __builtin_amdgcn_global_load_lds((const __attribute__((address_space(1))) unsigned int*)g,
                                     (__attribute__((address_space(3))) unsigned int*)l, 16, 0, 0);
}

// ---------------- W prep: WT[192][1024] bf16 (rows 0..63 k-scaled, 64..127 q, 128..191 v) ----------
__global__ __launch_bounds__(256) void wprep_kernel(const float* __restrict__ Wk,
                                                    const float* __restrict__ Wq,
                                                    const float* __restrict__ Wv,
                                                    unsigned short* __restrict__ WT){
    __shared__ float lw[1024][8];
    int w = blockIdx.x, n0 = blockIdx.y * 8, tid = threadIdx.x;
    const float* src = (w == 0) ? Wk : (w == 1) ? Wq : Wv;
    float scale = (w == 0) ? 0.18033688011112042f : 1.0f;  // 0.125 * log2(e)
    for (int it = 0; it < 8; ++it){
        int idx = it * 256 + tid;
        int k = idx >> 1, half = idx & 1;
        f32x4 v = *(const f32x4*)(src + k * 64 + n0 + half * 4);
        *(f32x4*)&lw[k][half * 4] = v;
    }
    __syncthreads();
    int n = tid >> 5, kc = (tid & 31) * 32;
    unsigned short* dst = WT + (size_t)((w * 64 + n0 + n) * 1024 + kc);
    #pragma unroll
    for (int c = 0; c < 4; c++){
        s16x8 v;
        #pragma unroll
        for (int e = 0; e < 8; e++)
            v[e] = (short)bf16one(lw[kc + c * 8 + e][n] * scale);
        *(s16x8*)(dst + c * 8) = v;
    }
}

// ---------------- Projections v5 (epilogue: plain vT[b][h][t]): 512 blocks x 512 thr ----------------
__global__ __launch_bounds__(512, 4) void proj_kernel(const float* __restrict__ x,
                                                      const unsigned short* __restrict__ WT,
                                                      unsigned short* __restrict__ kb,
                                                      unsigned short* __restrict__ qb,
                                                      unsigned short* __restrict__ vT){
    __shared__ unsigned short smem[32 * 200];  // dbuf x-tiles [0..2047],[2048..4095]; out-tile [32][200]
    int tid = threadIdx.x; int l = tid & 63;
    int w = tid >> 6;
    int lr = l & 15, lg = l >> 4;
    int mh = w >> 2, nsub = w & 3;
    int row0 = blockIdx.x * 32;
    int b = row0 >> 11, t0 = row0 & 2047;

    // staging map: thread -> (srow 0..31, chunk 0..7, half); swizzle chunk ^= srow&7 (write side)
    int srow = tid >> 4, sub = tid & 15;
    int chunk = sub >> 1, half = sub & 1;
    const float* sg = x + (size_t)(row0 + srow) * 1024 + chunk * 8 + half * 4;
    unsigned short* swr = smem + srow * 64 + ((chunk ^ (srow & 7)) * 8) + half * 4;

    // A ds-read addrs (buf0): row = mh*16+lr, chunk = (kc*4+lg)^(row&7)
    const unsigned short* ard[2];
    int ar = mh * 16 + lr;
    #pragma unroll
    for (int kc = 0; kc < 2; kc++)
        ard[kc] = smem + ar * 64 + (((kc * 4 + lg) ^ (ar & 7)) * 8);

    // B global base pointers (3 n-tiles per wave)
    const unsigned short* bp[3];
    #pragma unroll
    for (int nn = 0; nn < 3; nn++)
        bp[nn] = WT + (size_t)((nsub * 3 + nn) * 16 + lr) * 1024 + lg * 8;

    f32x4 acc[3] = {};

    // prologue: stage k0=0 into buf0
    f32x4 xa = *(const f32x4*)(sg);
    {
        u32x2 pk;
        pk[0] = bf16pack(xa[0], xa[1]); pk[1] = bf16pack(xa[2], xa[3]);
        *(u32x2*)swr = pk;
    }
    int cur = 0;
    for (int k0 = 0; k0 < 1024; k0 += 64){
        __syncthreads();
        // B loads for this step
        s16x8 bf[3][2];
        #pragma unroll
        for (int nn = 0; nn < 3; nn++){
            bf[nn][0] = *(const s16x8*)(bp[nn] + k0);
            bf[nn][1] = *(const s16x8*)(bp[nn] + k0 + 32);
        }
        // x load for next step (clamped, unconditional -> no UB)
        int kn = (k0 + 64 < 1024) ? (k0 + 64) : 960;
        xa = *(const f32x4*)(sg + kn);
        // A fragments from LDS (buffer cur)
        s16x8 af[2];
        #pragma unroll
        for (int kc = 0; kc < 2; kc++)
            af[kc] = *(const s16x8*)(ard[kc] + cur * 2048);
        __builtin_amdgcn_sched_barrier(0);
        #pragma unroll
        for (int nn = 0; nn < 3; nn++){
            acc[nn] = __builtin_amdgcn_mfma_f32_16x16x32_bf16(af[0], bf[nn][0], acc[nn], 0, 0, 0);
            acc[nn] = __builtin_amdgcn_mfma_f32_16x16x32_bf16(af[1], bf[nn][1], acc[nn], 0, 0, 0);
        }
        // convert + stage-write next buf (last iter redundant; overwritten after barrier)
        {
            u32x2 pk;
            pk[0] = bf16pack(xa[0], xa[1]); pk[1] = bf16pack(xa[2], xa[3]);
            *(u32x2*)(swr + (cur ^ 1) * 2048) = pk;
        }
        cur ^= 1;
    }
    __syncthreads();
    // epilogue: acc -> out tile [32][200] bf16 (cols 0..63 k, 64..127 q, 128..191 v)
    #pragma unroll
    for (int nn = 0; nn < 3; nn++){
        int col = (nsub * 3 + nn) * 16 + lr;
        int row = mh * 16 + lg * 4;
        #pragma unroll
        for (int r = 0; r < 4; r++)
            smem[(row + r) * 200 + col] = bf16one(acc[nn][r]);
    }
    __syncthreads();
    {
        // k|q rows: 32 rows x 128 cols, 16B per thread
        int r2 = tid >> 4, c2 = (tid & 15) * 8;
        const unsigned short* srowp = smem + r2 * 200 + c2;
        unsigned short* dst = (c2 < 64)
            ? kb + (size_t)(b * 2048 + t0 + r2) * 64 + c2
            : qb + (size_t)(b * 2048 + t0 + r2) * 64 + (c2 - 64);
        *(s16x8*)(dst) = *(const s16x8*)(srowp);
        if (tid < 256){
            // plain transpose: vT[b][h][t]
            int h = tid >> 2, q3 = tid & 3;
            s16x8 vv;
            #pragma unroll
            for (int e = 0; e < 8; e++)
                vv[e] = smem[(q3 * 8 + e) * 200 + 128 + h];
            *(s16x8*)(vT + (size_t)(b * 64 + h) * 2048 + t0 + q3 * 8) = vv;
        }
    }
}

// ---------------- Flash attention v8: LDS-staged K/V (gload_lds DMA), 64-t tile, no s-split -----
// grid 256: b = bx&7 (XCD-pinned), bt = bx>>3 (t-tile). 4 waves own 16 t-rows each.
// K chunk [64s][64d] and V chunk [64h][64s] double-buffered in LDS, XOR-swizzled via
// pre-swizzled global source (linear DMA dest) + swizzled ds_read.
__global__ __launch_bounds__(256) void attn_kernel(const unsigned short* __restrict__ kb,
                                                   const unsigned short* __restrict__ qb,
                                                   const unsigned short* __restrict__ vT,
                                                   float* __restrict__ out){
    __shared__ unsigned short Klds[2][64 * 64];
    __shared__ unsigned short Vlds[2][64 * 64];
    int tid = threadIdx.x; int l = tid & 63; int w = tid >> 6;
    int lr = l & 15, lg = l >> 4;
    int bx = blockIdx.x;
    int b = bx & 7;
    int bt = bx >> 3;          // t-tile 0..31
    int t0 = bt * 64;
    int tw = t0 + w * 16;      // this wave's 16 t-rows
    const unsigned short* fqp = kb + (size_t)(b * 2048 + tw + lr) * 64 + lg * 8;
    s16x8 fq0 = *(const s16x8*)(fqp);
    s16x8 fq1 = *(const s16x8*)(fqp + 32);
    const unsigned short* qbb = qb + (size_t)b * 2048 * 64;
    const unsigned short* vbb = vT + (size_t)b * 64 * 2048;

    // staging: each wave issues 2 K + 2 V DMA instrs (8 rows of 128B each)
    int srhi = l >> 3;     // row within 8-row group
    int schk = l & 7;      // 16B chunk within 128B row
    f32x4 acc[4] = {};
    float mrun = -3.0e38f, lrun = 0.0f;

    // prologue: stage chunk 0 into buf 0
    #pragma unroll
    for (int t = 0; t < 2; t++){
        int ti = w * 2 + t;
        int row = ti * 8 + srhi;
        gload16(qbb + (size_t)row * 64 + ((schk ^ (row & 7)) * 8), &Klds[0][ti * 512]);
        gload16(vbb + (size_t)row * 2048 + ((schk ^ (row & 7)) * 8), &Vlds[0][ti * 512]);
    }
    __syncthreads();
    int cur = 0;
    for (int c = 0; c <= bt; ++c){
        // issue next-chunk stage (clamped; last iter redundant)
        int nc = (c + 1 <= bt) ? (c + 1) : bt;
        int ns0 = nc * 64;
        #pragma unroll
        for (int t = 0; t < 2; t++){
            int ti = w * 2 + t;
            int row = ti * 8 + srhi;
            gload16(qbb + (size_t)(ns0 + row) * 64 + ((schk ^ (row & 7)) * 8), &Klds[cur ^ 1][ti * 512]);
            gload16(vbb + (size_t)row * 2048 + ns0 + ((schk ^ (row & 7)) * 8), &Vlds[cur ^ 1][ti * 512]);
        }
        // ---- compute chunk c from LDS buf cur ----
        // S^T: C[s][t] = sum_d q[s][d]*k[t][d]; K-frag rows = s-local
        f32x4 Cs[4];
        #pragma unroll
        for (int n = 0; n < 4; n++){
            int r = n * 16 + lr;
            const unsigned short* ka = &Klds[cur][r * 64];
            s16x8 k0 = *(const s16x8*)(ka + ((lg       ^ (r & 7)) * 8));
            s16x8 k1 = *(const s16x8*)(ka + (((4 + lg) ^ (r & 7)) * 8));
            f32x4 z = {};
            z     = __builtin_amdgcn_mfma_f32_16x16x32_bf16(k0, fq0, z, 0, 0, 0);
            Cs[n] = __builtin_amdgcn_mfma_f32_16x16x32_bf16(k1, fq1, z, 0, 0, 0);
        }
        if (c == bt){  // diagonal chunk: mask s>t (s-local n*16+lg*4+r vs t-local 16w+lr)
            #pragma unroll
            for (int n = 0; n < 4; n++)
                #pragma unroll
                for (int r = 0; r < 4; r++)
                    if (n * 16 + lg * 4 + r > w * 16 + lr) Cs[n][r] = -3.0e38f;
        }
        // online softmax over s for column t=lr
        float pm = -3.0e38f;
        #pragma unroll
        for (int n = 0; n < 4; n++)
            #pragma unroll
            for (int r = 0; r < 4; r++) pm = fmaxf(pm, Cs[n][r]);
        pm = fmaxf(pm, __shfl_xor(pm, 16));
        pm = fmaxf(pm, __shfl_xor(pm, 32));
        float mnew = fmaxf(mrun, pm);
        float scl = exp2f(mrun - mnew);
        float p[4][4]; float ps = 0.0f;
        #pragma unroll
        for (int n = 0; n < 4; n++)
            #pragma unroll
            for (int r = 0; r < 4; r++){ float e = exp2f(Cs[n][r] - mnew); p[n][r] = e; ps += e; }
        ps += __shfl_xor(ps, 16);
        ps += __shfl_xor(ps, 32);
        lrun = lrun * scl + ps;
        mrun = mnew;
        #pragma unroll
        for (int h16 = 0; h16 < 4; h16++) acc[h16] *= scl;
        s16x4 pb[4];
        #pragma unroll
        for (int n = 0; n < 4; n++){
            u32x2 t; t[0] = bf16pack(p[n][0], p[n][1]); t[1] = bf16pack(p[n][2], p[n][3]);
            pb[n] = __builtin_bit_cast(s16x4, t);
        }
        // out^T: C[h][t] += V^T[h][s] * P^T[s][t]; V-frag: row=h-local, 8B at s-slice
        #pragma unroll
        for (int h16 = 0; h16 < 4; h16++){
            int r = h16 * 16 + lr;
            const unsigned short* va = &Vlds[cur][r * 64];
            #pragma unroll
            for (int sl = 0; sl < 4; sl++){
                s16x4 fv = *(const s16x4*)(va + (((sl * 2 + (lg >> 1)) ^ (r & 7)) * 8) + (lg & 1) * 4);
                acc[h16] = __builtin_amdgcn_mfma_f32_16x16x16bf16_1k(fv, pb[sl], acc[h16], 0, 0, 0);
            }
        }
        __syncthreads();  // drains this iter's DMA (vmcnt) + all ds_reads, then barrier
        cur ^= 1;
    }
    float inv = 1.0f / lrun;
    #pragma unroll
    for (int h16 = 0; h16 < 4; h16++){
        f32x4 o = acc[h16] * inv;
        *(f32x4*)(out + (size_t)(b * 2048 + tw + lr) * 64 + h16 * 16 + lg * 4) = o;
    }
}

extern "C" void kernel_launch(void* const* d_in, const int* in_sizes, int n_in,
                              void* d_out, int out_size, void* d_ws, size_t ws_size,
                              hipStream_t stream) {
    const float* x  = (const float*)d_in[0];
    const float* Wk = (const float*)d_in[1];
    const float* Wq = (const float*)d_in[2];
    const float* Wv = (const float*)d_in[3];
    float* out = (float*)d_out;
    char* ws = (char*)d_ws;
    if (ws_size < (size_t)7 * 1024 * 1024) return;
    unsigned short* WT = (unsigned short*)(ws);              // 384 KB
    unsigned short* kb = (unsigned short*)(ws + (1u << 20)); // 2 MB (k * 0.125*log2e)
    unsigned short* qb = (unsigned short*)(ws + (3u << 20)); // 2 MB
    unsigned short* vT = (unsigned short*)(ws + (5u << 20)); // 2 MB ([b][h][t])
    hipLaunchKernelGGL(wprep_kernel, dim3(3, 8), dim3(256), 0, stream, Wk, Wq, Wv, WT);
    hipLaunchKernelGGL(proj_kernel, dim3(512), dim3(512), 0, stream, x, WT, kb, qb, vT);
    hipLaunchKernelGGL(attn_kernel, dim3(256), dim3(256), 0, stream, kb, qb, vT, out);
}

// Round 9
// 68.183 us; speedup vs baseline: 1.7328x; 1.4782x over previous
//
#include <hip/hip_runtime.h>
#include <hip/hip_bf16.h>
#include <stdint.h>

// Shapes: B=8, T=2048, E=1024, H=64
// wei[t][s] = k[t]·q[s] * 0.125 (k plays "query"), causal s<=t.
// 0.125*log2(e) folded into Wk so softmax uses exp2 directly.

typedef __attribute__((ext_vector_type(4))) float f32x4;
typedef __attribute__((ext_vector_type(4))) short s16x4;
typedef __attribute__((ext_vector_type(8))) short s16x8;
typedef __attribute__((ext_vector_type(2))) unsigned int u32x2;
typedef __attribute__((ext_vector_type(4))) unsigned int u32x4;

__device__ __forceinline__ unsigned bf16pack(float a, float b){
    unsigned ua = __builtin_bit_cast(unsigned, a);
    unsigned ub = __builtin_bit_cast(unsigned, b);
    return ((ua + 0x8000u) >> 16) | ((ub + 0x8000u) & 0xffff0000u);
}
__device__ __forceinline__ unsigned short bf16one(float a){
    return (unsigned short)((__builtin_bit_cast(unsigned, a) + 0x8000u) >> 16);
}
// async global->LDS DMA, 16B per lane; LDS dest = uniform base + lane*16 (linear)
__device__ __forceinline__ void gload16(const void* g, unsigned short* l){
    __builtin_amdgcn_global_load_lds((const __attribute__((address_space(1))) unsigned int*)g,
                                     (__attribute__((address_space(3))) unsigned int*)l, 16, 0, 0);
}

// ---------------- W prep: WT[192][1024] bf16 (rows 0..63 k-scaled, 64..127 q, 128..191 v) ----------
__global__ __launch_bounds__(256) void wprep_kernel(const float* __restrict__ Wk,
                                                    const float* __restrict__ Wq,
                                                    const float* __restrict__ Wv,
                                                    unsigned short* __restrict__ WT){
    __shared__ float lw[1024][8];
    int w = blockIdx.x, n0 = blockIdx.y * 8, tid = threadIdx.x;
    const float* src = (w == 0) ? Wk : (w == 1) ? Wq : Wv;
    float scale = (w == 0) ? 0.18033688011112042f : 1.0f;  // 0.125 * log2(e)
    for (int it = 0; it < 8; ++it){
        int idx = it * 256 + tid;
        int k = idx >> 1, half = idx & 1;
        f32x4 v = *(const f32x4*)(src + k * 64 + n0 + half * 4);
        *(f32x4*)&lw[k][half * 4] = v;
    }
    __syncthreads();
    int n = tid >> 5, kc = (tid & 31) * 32;
    unsigned short* dst = WT + (size_t)((w * 64 + n0 + n) * 1024 + kc);
    #pragma unroll
    for (int c = 0; c < 4; c++){
        s16x8 v;
        #pragma unroll
        for (int e = 0; e < 8; e++)
            v[e] = (short)bf16one(lw[kc + c * 8 + e][n] * scale);
        *(s16x8*)(dst + c * 8) = v;
    }
}

// ---------------- Projections v10: full DMA staging (x AND WT), 512 blocks x 256 thr ----------------
// 32-row tiles; wave w = 3 n-tiles (w*3..w*3+2) x 2 m-frags. LDS 64 KB: x fp32 [2][32][64]
// (XOR-swizzled chunk^=(row&7)<<1 via pre-swizzled source) + WT slice [2][192][64] bf16
// (chunk^=row&7). Per step: 8 DMA instr/wave -> 12 MFMA -> 1 barrier. 2 blocks/CU.
__global__ __launch_bounds__(256) void proj_kernel(const float* __restrict__ x,
                                                   const unsigned short* __restrict__ WT,
                                                   unsigned short* __restrict__ kb,
                                                   unsigned short* __restrict__ qb,
                                                   unsigned short* __restrict__ vT){
    __shared__ unsigned short smem[32768];  // xb: 0/4096 (8KB each); wb: 8192/20480 (24KB each)
    int tid = threadIdx.x; int l = tid & 63; int w = tid >> 6;
    int lr = l & 15, lg = l >> 4;
    int row0 = blockIdx.x * 32;
    int b = row0 >> 11, t0 = row0 & 2047;
    const float* xbase = x + (size_t)row0 * 1024;

    auto stage = [&](int k0, int buf){
        // x fp32 tile [32 rows][64 floats]: 8 x 1KB DMA blocks, 2 per wave
        #pragma unroll
        for (int t = 0; t < 2; t++){
            int i = w * 2 + t;            // 1KB block 0..7
            int r = i * 4 + (l >> 4);     // row 0..31
            int c = l & 15;               // 16B chunk in 256B row
            gload16(xbase + (size_t)r * 1024 + k0 + ((c ^ ((r & 7) << 1)) * 4),
                    smem + buf * 4096 + i * 512);
        }
        // WT slice [192 rows][64 bf16]: 24 x 1KB blocks, 6 per wave
        #pragma unroll
        for (int u = 0; u < 6; u++){
            int i = w * 6 + u;            // 1KB block 0..23
            int r = i * 8 + (l >> 3);     // row 0..191
            int c = l & 7;                // 16B chunk in 128B row
            gload16(WT + (size_t)r * 1024 + k0 + ((c ^ (r & 7)) * 8),
                    smem + 8192 + buf * 12288 + i * 512);
        }
    };

    f32x4 acc[2][3] = {};
    stage(0, 0);
    __syncthreads();
    int cur = 0;
    for (int k0 = 0; k0 < 1024; k0 += 64){
        int kn = (k0 + 64 < 1024) ? (k0 + 64) : 960;
        stage(kn, cur ^ 1);
        // A fragments: fp32 from LDS -> bf16 pack
        s16x8 af[2][2];
        #pragma unroll
        for (int mf = 0; mf < 2; mf++){
            int r = mf * 16 + lr;
            const unsigned short* xrow = smem + cur * 4096 + r * 128;  // 256B rows
            #pragma unroll
            for (int kc = 0; kc < 2; kc++){
                int c0 = (kc * 8 + lg * 2) ^ ((r & 7) << 1);  // even; c1 = c0+1
                f32x4 v0 = *(const f32x4*)(xrow + c0 * 8);
                f32x4 v1 = *(const f32x4*)(xrow + c0 * 8 + 8);
                u32x4 pk;
                pk[0] = bf16pack(v0[0], v0[1]); pk[1] = bf16pack(v0[2], v0[3]);
                pk[2] = bf16pack(v1[0], v1[1]); pk[3] = bf16pack(v1[2], v1[3]);
                af[mf][kc] = __builtin_bit_cast(s16x8, pk);
            }
        }
        // B fragments + MFMA
        #pragma unroll
        for (int nn = 0; nn < 3; nn++){
            int r = (w * 3 + nn) * 16 + lr;
            const unsigned short* wrow = smem + 8192 + cur * 12288 + r * 64;  // 128B rows
            s16x8 b0 = *(const s16x8*)(wrow + ((lg       ^ (r & 7)) * 8));
            s16x8 b1 = *(const s16x8*)(wrow + (((4 + lg) ^ (r & 7)) * 8));
            acc[0][nn] = __builtin_amdgcn_mfma_f32_16x16x32_bf16(af[0][0], b0, acc[0][nn], 0, 0, 0);
            acc[0][nn] = __builtin_amdgcn_mfma_f32_16x16x32_bf16(af[0][1], b1, acc[0][nn], 0, 0, 0);
            acc[1][nn] = __builtin_amdgcn_mfma_f32_16x16x32_bf16(af[1][0], b0, acc[1][nn], 0, 0, 0);
            acc[1][nn] = __builtin_amdgcn_mfma_f32_16x16x32_bf16(af[1][1], b1, acc[1][nn], 0, 0, 0);
        }
        __syncthreads();  // drains this step's DMA (next buf) + LDS reads
        cur ^= 1;
    }
    // epilogue: acc -> out tile [32][200] bf16 (cols 0..63 k, 64..127 q, 128..191 v); reuses smem
    #pragma unroll
    for (int mf = 0; mf < 2; mf++)
        #pragma unroll
        for (int nn = 0; nn < 3; nn++){
            int col = (w * 3 + nn) * 16 + lr;
            int row = mf * 16 + lg * 4;
            #pragma unroll
            for (int r = 0; r < 4; r++)
                smem[(row + r) * 200 + col] = bf16one(acc[mf][nn][r]);
        }
    __syncthreads();
    {
        // k|q rows: 32 rows x 128 cols, 32 ushorts per thread
        int r2 = tid >> 3, c2 = (tid & 7) * 16;
        const unsigned short* srowp = smem + r2 * 200 + c2;
        unsigned short* dst = (c2 < 64)
            ? kb + (size_t)(b * 2048 + t0 + r2) * 64 + c2
            : qb + (size_t)(b * 2048 + t0 + r2) * 64 + (c2 - 64);
        *(s16x8*)(dst)     = *(const s16x8*)(srowp);
        *(s16x8*)(dst + 8) = *(const s16x8*)(srowp + 8);
        // plain transpose: vT[b][h][t]
        int h = tid >> 2, q3 = tid & 3;
        s16x8 vv;
        #pragma unroll
        for (int e = 0; e < 8; e++)
            vv[e] = smem[(q3 * 8 + e) * 200 + 128 + h];
        *(s16x8*)(vT + (size_t)(b * 64 + h) * 2048 + t0 + q3 * 8) = vv;
    }
}

// ---------------- Flash attention v8 (unchanged, passed r8): LDS-staged K/V via DMA ----------------
__global__ __launch_bounds__(256) void attn_kernel(const unsigned short* __restrict__ kb,
                                                   const unsigned short* __restrict__ qb,
                                                   const unsigned short* __restrict__ vT,
                                                   float* __restrict__ out){
    __shared__ unsigned short Klds[2][64 * 64];
    __shared__ unsigned short Vlds[2][64 * 64];
    int tid = threadIdx.x; int l = tid & 63; int w = tid >> 6;
    int lr = l & 15, lg = l >> 4;
    int bx = blockIdx.x;
    int b = bx & 7;
    int bt = bx >> 3;          // t-tile 0..31
    int t0 = bt * 64;
    int tw = t0 + w * 16;      // this wave's 16 t-rows
    const unsigned short* fqp = kb + (size_t)(b * 2048 + tw + lr) * 64 + lg * 8;
    s16x8 fq0 = *(const s16x8*)(fqp);
    s16x8 fq1 = *(const s16x8*)(fqp + 32);
    const unsigned short* qbb = qb + (size_t)b * 2048 * 64;
    const unsigned short* vbb = vT + (size_t)b * 64 * 2048;

    int srhi = l >> 3;     // row within 8-row group
    int schk = l & 7;      // 16B chunk within 128B row
    f32x4 acc[4] = {};
    float mrun = -3.0e38f, lrun = 0.0f;

    #pragma unroll
    for (int t = 0; t < 2; t++){
        int ti = w * 2 + t;
        int row = ti * 8 + srhi;
        gload16(qbb + (size_t)row * 64 + ((schk ^ (row & 7)) * 8), &Klds[0][ti * 512]);
        gload16(vbb + (size_t)row * 2048 + ((schk ^ (row & 7)) * 8), &Vlds[0][ti * 512]);
    }
    __syncthreads();
    int cur = 0;
    for (int c = 0; c <= bt; ++c){
        int nc = (c + 1 <= bt) ? (c + 1) : bt;
        int ns0 = nc * 64;
        #pragma unroll
        for (int t = 0; t < 2; t++){
            int ti = w * 2 + t;
            int row = ti * 8 + srhi;
            gload16(qbb + (size_t)(ns0 + row) * 64 + ((schk ^ (row & 7)) * 8), &Klds[cur ^ 1][ti * 512]);
            gload16(vbb + (size_t)row * 2048 + ns0 + ((schk ^ (row & 7)) * 8), &Vlds[cur ^ 1][ti * 512]);
        }
        f32x4 Cs[4];
        #pragma unroll
        for (int n = 0; n < 4; n++){
            int r = n * 16 + lr;
            const unsigned short* ka = &Klds[cur][r * 64];
            s16x8 k0 = *(const s16x8*)(ka + ((lg       ^ (r & 7)) * 8));
            s16x8 k1 = *(const s16x8*)(ka + (((4 + lg) ^ (r & 7)) * 8));
            f32x4 z = {};
            z     = __builtin_amdgcn_mfma_f32_16x16x32_bf16(k0, fq0, z, 0, 0, 0);
            Cs[n] = __builtin_amdgcn_mfma_f32_16x16x32_bf16(k1, fq1, z, 0, 0, 0);
        }
        if (c == bt){
            #pragma unroll
            for (int n = 0; n < 4; n++)
                #pragma unroll
                for (int r = 0; r < 4; r++)
                    if (n * 16 + lg * 4 + r > w * 16 + lr) Cs[n][r] = -3.0e38f;
        }
        float pm = -3.0e38f;
        #pragma unroll
        for (int n = 0; n < 4; n++)
            #pragma unroll
            for (int r = 0; r < 4; r++) pm = fmaxf(pm, Cs[n][r]);
        pm = fmaxf(pm, __shfl_xor(pm, 16));
        pm = fmaxf(pm, __shfl_xor(pm, 32));
        float mnew = fmaxf(mrun, pm);
        float scl = exp2f(mrun - mnew);
        float p[4][4]; float ps = 0.0f;
        #pragma unroll
        for (int n = 0; n < 4; n++)
            #pragma unroll
            for (int r = 0; r < 4; r++){ float e = exp2f(Cs[n][r] - mnew); p[n][r] = e; ps += e; }
        ps += __shfl_xor(ps, 16);
        ps += __shfl_xor(ps, 32);
        lrun = lrun * scl + ps;
        mrun = mnew;
        #pragma unroll
        for (int h16 = 0; h16 < 4; h16++) acc[h16] *= scl;
        s16x4 pb[4];
        #pragma unroll
        for (int n = 0; n < 4; n++){
            u32x2 t; t[0] = bf16pack(p[n][0], p[n][1]); t[1] = bf16pack(p[n][2], p[n][3]);
            pb[n] = __builtin_bit_cast(s16x4, t);
        }
        #pragma unroll
        for (int h16 = 0; h16 < 4; h16++){
            int r = h16 * 16 + lr;
            const unsigned short* va = &Vlds[cur][r * 64];
            #pragma unroll
            for (int sl = 0; sl < 4; sl++){
                s16x4 fv = *(const s16x4*)(va + (((sl * 2 + (lg >> 1)) ^ (r & 7)) * 8) + (lg & 1) * 4);
                acc[h16] = __builtin_amdgcn_mfma_f32_16x16x16bf16_1k(fv, pb[sl], acc[h16], 0, 0, 0);
            }
        }
        __syncthreads();
        cur ^= 1;
    }
    float inv = 1.0f / lrun;
    #pragma unroll
    for (int h16 = 0; h16 < 4; h16++){
        f32x4 o = acc[h16] * inv;
        *(f32x4*)(out + (size_t)(b * 2048 + tw + lr) * 64 + h16 * 16 + lg * 4) = o;
    }
}

extern "C" void kernel_launch(void* const* d_in, const int* in_sizes, int n_in,
                              void* d_out, int out_size, void* d_ws, size_t ws_size,
                              hipStream_t stream) {
    const float* x  = (const float*)d_in[0];
    const float* Wk = (const float*)d_in[1];
    const float* Wq = (const float*)d_in[2];
    const float* Wv = (const float*)d_in[3];
    float* out = (float*)d_out;
    char* ws = (char*)d_ws;
    if (ws_size < (size_t)7 * 1024 * 1024) return;
    unsigned short* WT = (unsigned short*)(ws);              // 384 KB
    unsigned short* kb = (unsigned short*)(ws + (1u << 20)); // 2 MB (k * 0.125*log2e)
    unsigned short* qb = (unsigned short*)(ws + (3u << 20)); // 2 MB
    unsigned short* vT = (unsigned short*)(ws + (5u << 20)); // 2 MB ([b][h][t])
    hipLaunchKernelGGL(wprep_kernel, dim3(3, 8), dim3(256), 0, stream, Wk, Wq, Wv, WT);
    hipLaunchKernelGGL(proj_kernel, dim3(512), dim3(256), 0, stream, x, WT, kb, qb, vT);
    hipLaunchKernelGGL(attn_kernel, dim3(256), dim3(256), 0, stream, kb, qb, vT, out);
}

// Round 10
// 54.525 us; speedup vs baseline: 2.1668x; 1.2505x over previous
//
#include <hip/hip_runtime.h>
#include <hip/hip_bf16.h>
#include <stdint.h>

// Shapes: B=8, T=2048, E=1024, H=64
// wei[t][s] = k[t]·q[s] * 0.125 (k plays "query"), causal s<=t.
// 0.125*log2(e) folded into Wk so softmax uses exp2 directly.

typedef __attribute__((ext_vector_type(4))) float f32x4;
typedef __attribute__((ext_vector_type(4))) short s16x4;
typedef __attribute__((ext_vector_type(8))) short s16x8;
typedef __attribute__((ext_vector_type(2))) unsigned int u32x2;
typedef __attribute__((ext_vector_type(4))) unsigned int u32x4;

__device__ __forceinline__ unsigned bf16pack(float a, float b){
    unsigned ua = __builtin_bit_cast(unsigned, a);
    unsigned ub = __builtin_bit_cast(unsigned, b);
    return ((ua + 0x8000u) >> 16) | ((ub + 0x8000u) & 0xffff0000u);
}
__device__ __forceinline__ unsigned short bf16one(float a){
    return (unsigned short)((__builtin_bit_cast(unsigned, a) + 0x8000u) >> 16);
}
// async global->LDS DMA, 16B per lane; LDS dest = uniform base + lane*16 (linear)
__device__ __forceinline__ void gload16(const void* g, unsigned short* l){
    __builtin_amdgcn_global_load_lds((const __attribute__((address_space(1))) unsigned int*)g,
                                     (__attribute__((address_space(3))) unsigned int*)l, 16, 0, 0);
}

// ---------------- W prep: WT[192][1024] bf16 (rows 0..63 k-scaled, 64..127 q, 128..191 v) ----------
__global__ __launch_bounds__(256) void wprep_kernel(const float* __restrict__ Wk,
                                                    const float* __restrict__ Wq,
                                                    const float* __restrict__ Wv,
                                                    unsigned short* __restrict__ WT){
    __shared__ float lw[1024][8];
    int w = blockIdx.x, n0 = blockIdx.y * 8, tid = threadIdx.x;
    const float* src = (w == 0) ? Wk : (w == 1) ? Wq : Wv;
    float scale = (w == 0) ? 0.18033688011112042f : 1.0f;  // 0.125 * log2(e)
    for (int it = 0; it < 8; ++it){
        int idx = it * 256 + tid;
        int k = idx >> 1, half = idx & 1;
        f32x4 v = *(const f32x4*)(src + k * 64 + n0 + half * 4);
        *(f32x4*)&lw[k][half * 4] = v;
    }
    __syncthreads();
    int n = tid >> 5, kc = (tid & 31) * 32;
    unsigned short* dst = WT + (size_t)((w * 64 + n0 + n) * 1024 + kc);
    #pragma unroll
    for (int c = 0; c < 4; c++){
        s16x8 v;
        #pragma unroll
        for (int e = 0; e < 8; e++)
            v[e] = (short)bf16one(lw[kc + c * 8 + e][n] * scale);
        *(s16x8*)(dst + c * 8) = v;
    }
}

// ---------------- Projections v10 (unchanged, passed r9): full DMA staging ----------------
__global__ __launch_bounds__(256) void proj_kernel(const float* __restrict__ x,
                                                   const unsigned short* __restrict__ WT,
                                                   unsigned short* __restrict__ kb,
                                                   unsigned short* __restrict__ qb,
                                                   unsigned short* __restrict__ vT){
    __shared__ unsigned short smem[32768];  // xb: 0/4096 (8KB each); wb: 8192/20480 (24KB each)
    int tid = threadIdx.x; int l = tid & 63; int w = tid >> 6;
    int lr = l & 15, lg = l >> 4;
    int row0 = blockIdx.x * 32;
    int b = row0 >> 11, t0 = row0 & 2047;
    const float* xbase = x + (size_t)row0 * 1024;

    auto stage = [&](int k0, int buf){
        #pragma unroll
        for (int t = 0; t < 2; t++){
            int i = w * 2 + t;
            int r = i * 4 + (l >> 4);
            int c = l & 15;
            gload16(xbase + (size_t)r * 1024 + k0 + ((c ^ ((r & 7) << 1)) * 4),
                    smem + buf * 4096 + i * 512);
        }
        #pragma unroll
        for (int u = 0; u < 6; u++){
            int i = w * 6 + u;
            int r = i * 8 + (l >> 3);
            int c = l & 7;
            gload16(WT + (size_t)r * 1024 + k0 + ((c ^ (r & 7)) * 8),
                    smem + 8192 + buf * 12288 + i * 512);
        }
    };

    f32x4 acc[2][3] = {};
    stage(0, 0);
    __syncthreads();
    int cur = 0;
    for (int k0 = 0; k0 < 1024; k0 += 64){
        int kn = (k0 + 64 < 1024) ? (k0 + 64) : 960;
        stage(kn, cur ^ 1);
        s16x8 af[2][2];
        #pragma unroll
        for (int mf = 0; mf < 2; mf++){
            int r = mf * 16 + lr;
            const unsigned short* xrow = smem + cur * 4096 + r * 128;
            #pragma unroll
            for (int kc = 0; kc < 2; kc++){
                int c0 = (kc * 8 + lg * 2) ^ ((r & 7) << 1);
                f32x4 v0 = *(const f32x4*)(xrow + c0 * 8);
                f32x4 v1 = *(const f32x4*)(xrow + c0 * 8 + 8);
                u32x4 pk;
                pk[0] = bf16pack(v0[0], v0[1]); pk[1] = bf16pack(v0[2], v0[3]);
                pk[2] = bf16pack(v1[0], v1[1]); pk[3] = bf16pack(v1[2], v1[3]);
                af[mf][kc] = __builtin_bit_cast(s16x8, pk);
            }
        }
        #pragma unroll
        for (int nn = 0; nn < 3; nn++){
            int r = (w * 3 + nn) * 16 + lr;
            const unsigned short* wrow = smem + 8192 + cur * 12288 + r * 64;
            s16x8 b0 = *(const s16x8*)(wrow + ((lg       ^ (r & 7)) * 8));
            s16x8 b1 = *(const s16x8*)(wrow + (((4 + lg) ^ (r & 7)) * 8));
            acc[0][nn] = __builtin_amdgcn_mfma_f32_16x16x32_bf16(af[0][0], b0, acc[0][nn], 0, 0, 0);
            acc[0][nn] = __builtin_amdgcn_mfma_f32_16x16x32_bf16(af[0][1], b1, acc[0][nn], 0, 0, 0);
            acc[1][nn] = __builtin_amdgcn_mfma_f32_16x16x32_bf16(af[1][0], b0, acc[1][nn], 0, 0, 0);
            acc[1][nn] = __builtin_amdgcn_mfma_f32_16x16x32_bf16(af[1][1], b1, acc[1][nn], 0, 0, 0);
        }
        __syncthreads();
        cur ^= 1;
    }
    #pragma unroll
    for (int mf = 0; mf < 2; mf++)
        #pragma unroll
        for (int nn = 0; nn < 3; nn++){
            int col = (w * 3 + nn) * 16 + lr;
            int row = mf * 16 + lg * 4;
            #pragma unroll
            for (int r = 0; r < 4; r++)
                smem[(row + r) * 200 + col] = bf16one(acc[mf][nn][r]);
        }
    __syncthreads();
    {
        int r2 = tid >> 3, c2 = (tid & 7) * 16;
        const unsigned short* srowp = smem + r2 * 200 + c2;
        unsigned short* dst = (c2 < 64)
            ? kb + (size_t)(b * 2048 + t0 + r2) * 64 + c2
            : qb + (size_t)(b * 2048 + t0 + r2) * 64 + (c2 - 64);
        *(s16x8*)(dst)     = *(const s16x8*)(srowp);
        *(s16x8*)(dst + 8) = *(const s16x8*)(srowp + 8);
        int h = tid >> 2, q3 = tid & 3;
        s16x8 vv;
        #pragma unroll
        for (int e = 0; e < 8; e++)
            vv[e] = smem[(q3 * 8 + e) * 200 + 128 + h];
        *(s16x8*)(vT + (size_t)(b * 64 + h) * 2048 + t0 + q3 * 8) = vv;
    }
}

// ============ attn partial chunk body (shared by v8 fallback and v9 strips) ============
// Computes one 64-s chunk: QK^T from Klds, online softmax, PV from Vlds.
// All state passed by reference. Identical math to the r8-passing kernel.

// ---------------- attn v9 phase A: 512 balanced strip jobs (2 blocks/CU) ----------------
// bx: b = bx&7 (XCD-pinned); r = bx>>3 (0..63): bt = 31-(r>>1) (heavy first), strip = r&1.
// Strip processes chunks c = strip, strip+2, ... <= bt. Strip0 -> raw acc into out + ml0;
// strip1 -> acc1 (ws) + ml1. Merge kernel combines.
__global__ __launch_bounds__(256) void attn_part_kernel(const unsigned short* __restrict__ kb,
                                                        const unsigned short* __restrict__ qb,
                                                        const unsigned short* __restrict__ vT,
                                                        float* __restrict__ out,
                                                        float* __restrict__ acc1,
                                                        float* __restrict__ ml0,
                                                        float* __restrict__ ml1){
    __shared__ unsigned short Klds[2][64 * 64];
    __shared__ unsigned short Vlds[2][64 * 64];
    int tid = threadIdx.x; int l = tid & 63; int w = tid >> 6;
    int lr = l & 15, lg = l >> 4;
    int bx = blockIdx.x;
    int b = bx & 7;
    int r9 = bx >> 3;
    int bt = 31 - (r9 >> 1);
    int strip = r9 & 1;
    int t0 = bt * 64;
    int tw = t0 + w * 16;
    const unsigned short* fqp = kb + (size_t)(b * 2048 + tw + lr) * 64 + lg * 8;
    s16x8 fq0 = *(const s16x8*)(fqp);
    s16x8 fq1 = *(const s16x8*)(fqp + 32);
    const unsigned short* qbb = qb + (size_t)b * 2048 * 64;
    const unsigned short* vbb = vT + (size_t)b * 64 * 2048;

    int srhi = l >> 3;
    int schk = l & 7;
    f32x4 acc[4] = {};
    float mrun = -3.0e38f, lrun = 0.0f;

    // prologue: stage chunk 'strip' into buf 0 (address valid even if strip > bt)
    {
        int s0 = strip * 64;
        #pragma unroll
        for (int t = 0; t < 2; t++){
            int ti = w * 2 + t;
            int row = ti * 8 + srhi;
            gload16(qbb + (size_t)(s0 + row) * 64 + ((schk ^ (row & 7)) * 8), &Klds[0][ti * 512]);
            gload16(vbb + (size_t)row * 2048 + s0 + ((schk ^ (row & 7)) * 8), &Vlds[0][ti * 512]);
        }
    }
    __syncthreads();
    int cur = 0;
    for (int c = strip; c <= bt; c += 2){
        int nc = (c + 2 <= bt) ? (c + 2) : c;
        int ns0 = nc * 64;
        #pragma unroll
        for (int t = 0; t < 2; t++){
            int ti = w * 2 + t;
            int row = ti * 8 + srhi;
            gload16(qbb + (size_t)(ns0 + row) * 64 + ((schk ^ (row & 7)) * 8), &Klds[cur ^ 1][ti * 512]);
            gload16(vbb + (size_t)row * 2048 + ns0 + ((schk ^ (row & 7)) * 8), &Vlds[cur ^ 1][ti * 512]);
        }
        f32x4 Cs[4];
        #pragma unroll
        for (int n = 0; n < 4; n++){
            int r = n * 16 + lr;
            const unsigned short* ka = &Klds[cur][r * 64];
            s16x8 k0 = *(const s16x8*)(ka + ((lg       ^ (r & 7)) * 8));
            s16x8 k1 = *(const s16x8*)(ka + (((4 + lg) ^ (r & 7)) * 8));
            f32x4 z = {};
            z     = __builtin_amdgcn_mfma_f32_16x16x32_bf16(k0, fq0, z, 0, 0, 0);
            Cs[n] = __builtin_amdgcn_mfma_f32_16x16x32_bf16(k1, fq1, z, 0, 0, 0);
        }
        if (c == bt){
            #pragma unroll
            for (int n = 0; n < 4; n++)
                #pragma unroll
                for (int r = 0; r < 4; r++)
                    if (n * 16 + lg * 4 + r > w * 16 + lr) Cs[n][r] = -3.0e38f;
        }
        float pm = -3.0e38f;
        #pragma unroll
        for (int n = 0; n < 4; n++)
            #pragma unroll
            for (int r = 0; r < 4; r++) pm = fmaxf(pm, Cs[n][r]);
        pm = fmaxf(pm, __shfl_xor(pm, 16));
        pm = fmaxf(pm, __shfl_xor(pm, 32));
        float mnew = fmaxf(mrun, pm);
        float scl = exp2f(mrun - mnew);
        float p[4][4]; float ps = 0.0f;
        #pragma unroll
        for (int n = 0; n < 4; n++)
            #pragma unroll
            for (int r = 0; r < 4; r++){ float e = exp2f(Cs[n][r] - mnew); p[n][r] = e; ps += e; }
        ps += __shfl_xor(ps, 16);
        ps += __shfl_xor(ps, 32);
        lrun = lrun * scl + ps;
        mrun = mnew;
        #pragma unroll
        for (int h16 = 0; h16 < 4; h16++) acc[h16] *= scl;
        s16x4 pb[4];
        #pragma unroll
        for (int n = 0; n < 4; n++){
            u32x2 t; t[0] = bf16pack(p[n][0], p[n][1]); t[1] = bf16pack(p[n][2], p[n][3]);
            pb[n] = __builtin_bit_cast(s16x4, t);
        }
        #pragma unroll
        for (int h16 = 0; h16 < 4; h16++){
            int r = h16 * 16 + lr;
            const unsigned short* va = &Vlds[cur][r * 64];
            #pragma unroll
            for (int sl = 0; sl < 4; sl++){
                s16x4 fv = *(const s16x4*)(va + (((sl * 2 + (lg >> 1)) ^ (r & 7)) * 8) + (lg & 1) * 4);
                acc[h16] = __builtin_amdgcn_mfma_f32_16x16x16bf16_1k(fv, pb[sl], acc[h16], 0, 0, 0);
            }
        }
        __syncthreads();
        cur ^= 1;
    }
    // write raw partial: strip0 -> out, strip1 -> acc1; ml per t-row
    float* accdst = (strip == 0) ? out : acc1;
    #pragma unroll
    for (int h16 = 0; h16 < 4; h16++)
        *(f32x4*)(accdst + (size_t)(b * 2048 + tw + lr) * 64 + h16 * 16 + lg * 4) = acc[h16];
    if (lg == 0){
        float* mlp = (strip == 0) ? ml0 : ml1;
        int idx = (b * 32 + bt) * 64 + w * 16 + lr;
        mlp[idx * 2]     = mrun;
        mlp[idx * 2 + 1] = lrun;
    }
}

// ---------------- attn v9 phase B: merge the two strips per tile ----------------
__global__ __launch_bounds__(256) void attn_merge_kernel(const float* __restrict__ acc1,
                                                         const float* __restrict__ ml0,
                                                         const float* __restrict__ ml1,
                                                         float* __restrict__ out){
    int bt = blockIdx.x, b = blockIdx.y;
    int tid = threadIdx.x;
    int row = tid >> 2, cg = (tid & 3) * 16;
    int mlidx = ((b * 32 + bt) * 64 + row) * 2;
    float m0 = ml0[mlidx], l0 = ml0[mlidx + 1];
    float m1 = ml1[mlidx], l1 = ml1[mlidx + 1];
    float mg = fmaxf(m0, m1);
    float w0 = exp2f(m0 - mg), w1 = exp2f(m1 - mg);
    float inv = 1.0f / (l0 * w0 + l1 * w1);
    size_t base = (size_t)(b * 2048 + bt * 64 + row) * 64 + cg;
    #pragma unroll
    for (int g = 0; g < 4; g++){
        f32x4 a0 = *(const f32x4*)(out + base + g * 4);
        f32x4 a1 = *(const f32x4*)(acc1 + base + g * 4);
        f32x4 o = (a0 * w0 + a1 * w1) * inv;
        *(f32x4*)(out + base + g * 4) = o;
    }
}

// ---------------- Flash attention v8 (fallback if ws too small; passed r8/r9) ----------------
__global__ __launch_bounds__(256) void attn_kernel(const unsigned short* __restrict__ kb,
                                                   const unsigned short* __restrict__ qb,
                                                   const unsigned short* __restrict__ vT,
                                                   float* __restrict__ out){
    __shared__ unsigned short Klds[2][64 * 64];
    __shared__ unsigned short Vlds[2][64 * 64];
    int tid = threadIdx.x; int l = tid & 63; int w = tid >> 6;
    int lr = l & 15, lg = l >> 4;
    int bx = blockIdx.x;
    int b = bx & 7;
    int bt = bx >> 3;
    int t0 = bt * 64;
    int tw = t0 + w * 16;
    const unsigned short* fqp = kb + (size_t)(b * 2048 + tw + lr) * 64 + lg * 8;
    s16x8 fq0 = *(const s16x8*)(fqp);
    s16x8 fq1 = *(const s16x8*)(fqp + 32);
    const unsigned short* qbb = qb + (size_t)b * 2048 * 64;
    const unsigned short* vbb = vT + (size_t)b * 64 * 2048;
    int srhi = l >> 3;
    int schk = l & 7;
    f32x4 acc[4] = {};
    float mrun = -3.0e38f, lrun = 0.0f;
    #pragma unroll
    for (int t = 0; t < 2; t++){
        int ti = w * 2 + t;
        int row = ti * 8 + srhi;
        gload16(qbb + (size_t)row * 64 + ((schk ^ (row & 7)) * 8), &Klds[0][ti * 512]);
        gload16(vbb + (size_t)row * 2048 + ((schk ^ (row & 7)) * 8), &Vlds[0][ti * 512]);
    }
    __syncthreads();
    int cur = 0;
    for (int c = 0; c <= bt; ++c){
        int nc = (c + 1 <= bt) ? (c + 1) : bt;
        int ns0 = nc * 64;
        #pragma unroll
        for (int t = 0; t < 2; t++){
            int ti = w * 2 + t;
            int row = ti * 8 + srhi;
            gload16(qbb + (size_t)(ns0 + row) * 64 + ((schk ^ (row & 7)) * 8), &Klds[cur ^ 1][ti * 512]);
            gload16(vbb + (size_t)row * 2048 + ns0 + ((schk ^ (row & 7)) * 8), &Vlds[cur ^ 1][ti * 512]);
        }
        f32x4 Cs[4];
        #pragma unroll
        for (int n = 0; n < 4; n++){
            int r = n * 16 + lr;
            const unsigned short* ka = &Klds[cur][r * 64];
            s16x8 k0 = *(const s16x8*)(ka + ((lg       ^ (r & 7)) * 8));
            s16x8 k1 = *(const s16x8*)(ka + (((4 + lg) ^ (r & 7)) * 8));
            f32x4 z = {};
            z     = __builtin_amdgcn_mfma_f32_16x16x32_bf16(k0, fq0, z, 0, 0, 0);
            Cs[n] = __builtin_amdgcn_mfma_f32_16x16x32_bf16(k1, fq1, z, 0, 0, 0);
        }
        if (c == bt){
            #pragma unroll
            for (int n = 0; n < 4; n++)
                #pragma unroll
                for (int r = 0; r < 4; r++)
                    if (n * 16 + lg * 4 + r > w * 16 + lr) Cs[n][r] = -3.0e38f;
        }
        float pm = -3.0e38f;
        #pragma unroll
        for (int n = 0; n < 4; n++)
            #pragma unroll
            for (int r = 0; r < 4; r++) pm = fmaxf(pm, Cs[n][r]);
        pm = fmaxf(pm, __shfl_xor(pm, 16));
        pm = fmaxf(pm, __shfl_xor(pm, 32));
        float mnew = fmaxf(mrun, pm);
        float scl = exp2f(mrun - mnew);
        float p[4][4]; float ps = 0.0f;
        #pragma unroll
        for (int n = 0; n < 4; n++)
            #pragma unroll
            for (int r = 0; r < 4; r++){ float e = exp2f(Cs[n][r] - mnew); p[n][r] = e; ps += e; }
        ps += __shfl_xor(ps, 16);
        ps += __shfl_xor(ps, 32);
        lrun = lrun * scl + ps;
        mrun = mnew;
        #pragma unroll
        for (int h16 = 0; h16 < 4; h16++) acc[h16] *= scl;
        s16x4 pb[4];
        #pragma unroll
        for (int n = 0; n < 4; n++){
            u32x2 t; t[0] = bf16pack(p[n][0], p[n][1]); t[1] = bf16pack(p[n][2], p[n][3]);
            pb[n] = __builtin_bit_cast(s16x4, t);
        }
        #pragma unroll
        for (int h16 = 0; h16 < 4; h16++){
            int r = h16 * 16 + lr;
            const unsigned short* va = &Vlds[cur][r * 64];
            #pragma unroll
            for (int sl = 0; sl < 4; sl++){
                s16x4 fv = *(const s16x4*)(va + (((sl * 2 + (lg >> 1)) ^ (r & 7)) * 8) + (lg & 1) * 4);
                acc[h16] = __builtin_amdgcn_mfma_f32_16x16x16bf16_1k(fv, pb[sl], acc[h16], 0, 0, 0);
            }
        }
        __syncthreads();
        cur ^= 1;
    }
    float inv = 1.0f / lrun;
    #pragma unroll
    for (int h16 = 0; h16 < 4; h16++){
        f32x4 o = acc[h16] * inv;
        *(f32x4*)(out + (size_t)(b * 2048 + tw + lr) * 64 + h16 * 16 + lg * 4) = o;
    }
}

extern "C" void kernel_launch(void* const* d_in, const int* in_sizes, int n_in,
                              void* d_out, int out_size, void* d_ws, size_t ws_size,
                              hipStream_t stream) {
    const float* x  = (const float*)d_in[0];
    const float* Wk = (const float*)d_in[1];
    const float* Wq = (const float*)d_in[2];
    const float* Wv = (const float*)d_in[3];
    float* out = (float*)d_out;
    char* ws = (char*)d_ws;
    if (ws_size < (size_t)7 * 1024 * 1024) return;
    unsigned short* WT = (unsigned short*)(ws);              // 384 KB
    unsigned short* kb = (unsigned short*)(ws + (1u << 20)); // 2 MB (k * 0.125*log2e)
    unsigned short* qb = (unsigned short*)(ws + (3u << 20)); // 2 MB
    unsigned short* vT = (unsigned short*)(ws + (5u << 20)); // 2 MB ([b][h][t])
    hipLaunchKernelGGL(wprep_kernel, dim3(3, 8), dim3(256), 0, stream, Wk, Wq, Wv, WT);
    hipLaunchKernelGGL(proj_kernel, dim3(512), dim3(256), 0, stream, x, WT, kb, qb, vT);
    if (ws_size >= (size_t)12 * 1024 * 1024){
        float* acc1 = (float*)(ws + ((size_t)7 << 20));        // 4 MB
        float* ml0  = (float*)(ws + ((size_t)11 << 20));       // 128 KB
        float* ml1  = (float*)(ws + ((size_t)11 << 20) + (128u << 10));
        hipLaunchKernelGGL(attn_part_kernel, dim3(512), dim3(256), 0, stream,
                           kb, qb, vT, out, acc1, ml0, ml1);
        hipLaunchKernelGGL(attn_merge_kernel, dim3(32, 8), dim3(256), 0, stream,
                           acc1, ml0, ml1, out);
    } else {
        hipLaunchKernelGGL(attn_kernel, dim3(256), dim3(256), 0, stream, kb, qb, vT, out);
    }
}

// Round 11
// 50.211 us; speedup vs baseline: 2.3530x; 1.0859x over previous
//
#include <hip/hip_runtime.h>
#include <hip/hip_bf16.h>
#include <stdint.h>

// Shapes: B=8, T=2048, E=1024, H=64
// wei[t][s] = k[t]·q[s] * 0.125 (k plays "query"), causal s<=t.
// 0.125*log2(e) folded into Wk so softmax uses exp2 directly.

typedef __attribute__((ext_vector_type(4))) float f32x4;
typedef __attribute__((ext_vector_type(4))) short s16x4;
typedef __attribute__((ext_vector_type(8))) short s16x8;
typedef __attribute__((ext_vector_type(2))) unsigned int u32x2;
typedef __attribute__((ext_vector_type(4))) unsigned int u32x4;

__device__ __forceinline__ unsigned bf16pack(float a, float b){
    unsigned ua = __builtin_bit_cast(unsigned, a);
    unsigned ub = __builtin_bit_cast(unsigned, b);
    return ((ua + 0x8000u) >> 16) | ((ub + 0x8000u) & 0xffff0000u);
}
__device__ __forceinline__ unsigned short bf16one(float a){
    return (unsigned short)((__builtin_bit_cast(unsigned, a) + 0x8000u) >> 16);
}
// async global->LDS DMA, 16B per lane; LDS dest = uniform base + lane*16 (linear)
__device__ __forceinline__ void gload16(const void* g, unsigned short* l){
    __builtin_amdgcn_global_load_lds((const __attribute__((address_space(1))) unsigned int*)g,
                                     (__attribute__((address_space(3))) unsigned int*)l, 16, 0, 0);
}

// ---------------- W prep: WT[192][1024] bf16 (rows 0..63 k-scaled, 64..127 q, 128..191 v) ----------
__global__ __launch_bounds__(256) void wprep_kernel(const float* __restrict__ Wk,
                                                    const float* __restrict__ Wq,
                                                    const float* __restrict__ Wv,
                                                    unsigned short* __restrict__ WT){
    __shared__ float lw[1024][8];
    int w = blockIdx.x, n0 = blockIdx.y * 8, tid = threadIdx.x;
    const float* src = (w == 0) ? Wk : (w == 1) ? Wq : Wv;
    float scale = (w == 0) ? 0.18033688011112042f : 1.0f;  // 0.125 * log2(e)
    for (int it = 0; it < 8; ++it){
        int idx = it * 256 + tid;
        int k = idx >> 1, half = idx & 1;
        f32x4 v = *(const f32x4*)(src + k * 64 + n0 + half * 4);
        *(f32x4*)&lw[k][half * 4] = v;
    }
    __syncthreads();
    int n = tid >> 5, kc = (tid & 31) * 32;
    unsigned short* dst = WT + (size_t)((w * 64 + n0 + n) * 1024 + kc);
    #pragma unroll
    for (int c = 0; c < 4; c++){
        s16x8 v;
        #pragma unroll
        for (int e = 0; e < 8; e++)
            v[e] = (short)bf16one(lw[kc + c * 8 + e][n] * scale);
        *(s16x8*)(dst + c * 8) = v;
    }
}

// ---------------- Projections v10 (unchanged, passed r9/r10): full DMA staging ----------------
__global__ __launch_bounds__(256) void proj_kernel(const float* __restrict__ x,
                                                   const unsigned short* __restrict__ WT,
                                                   unsigned short* __restrict__ kb,
                                                   unsigned short* __restrict__ qb,
                                                   unsigned short* __restrict__ vT){
    __shared__ unsigned short smem[32768];  // xb: 0/4096 (8KB each); wb: 8192/20480 (24KB each)
    int tid = threadIdx.x; int l = tid & 63; int w = tid >> 6;
    int lr = l & 15, lg = l >> 4;
    int row0 = blockIdx.x * 32;
    int b = row0 >> 11, t0 = row0 & 2047;
    const float* xbase = x + (size_t)row0 * 1024;

    auto stage = [&](int k0, int buf){
        #pragma unroll
        for (int t = 0; t < 2; t++){
            int i = w * 2 + t;
            int r = i * 4 + (l >> 4);
            int c = l & 15;
            gload16(xbase + (size_t)r * 1024 + k0 + ((c ^ ((r & 7) << 1)) * 4),
                    smem + buf * 4096 + i * 512);
        }
        #pragma unroll
        for (int u = 0; u < 6; u++){
            int i = w * 6 + u;
            int r = i * 8 + (l >> 3);
            int c = l & 7;
            gload16(WT + (size_t)r * 1024 + k0 + ((c ^ (r & 7)) * 8),
                    smem + 8192 + buf * 12288 + i * 512);
        }
    };

    f32x4 acc[2][3] = {};
    stage(0, 0);
    __syncthreads();
    int cur = 0;
    for (int k0 = 0; k0 < 1024; k0 += 64){
        int kn = (k0 + 64 < 1024) ? (k0 + 64) : 960;
        stage(kn, cur ^ 1);
        s16x8 af[2][2];
        #pragma unroll
        for (int mf = 0; mf < 2; mf++){
            int r = mf * 16 + lr;
            const unsigned short* xrow = smem + cur * 4096 + r * 128;
            #pragma unroll
            for (int kc = 0; kc < 2; kc++){
                int c0 = (kc * 8 + lg * 2) ^ ((r & 7) << 1);
                f32x4 v0 = *(const f32x4*)(xrow + c0 * 8);
                f32x4 v1 = *(const f32x4*)(xrow + c0 * 8 + 8);
                u32x4 pk;
                pk[0] = bf16pack(v0[0], v0[1]); pk[1] = bf16pack(v0[2], v0[3]);
                pk[2] = bf16pack(v1[0], v1[1]); pk[3] = bf16pack(v1[2], v1[3]);
                af[mf][kc] = __builtin_bit_cast(s16x8, pk);
            }
        }
        #pragma unroll
        for (int nn = 0; nn < 3; nn++){
            int r = (w * 3 + nn) * 16 + lr;
            const unsigned short* wrow = smem + 8192 + cur * 12288 + r * 64;
            s16x8 b0 = *(const s16x8*)(wrow + ((lg       ^ (r & 7)) * 8));
            s16x8 b1 = *(const s16x8*)(wrow + (((4 + lg) ^ (r & 7)) * 8));
            acc[0][nn] = __builtin_amdgcn_mfma_f32_16x16x32_bf16(af[0][0], b0, acc[0][nn], 0, 0, 0);
            acc[0][nn] = __builtin_amdgcn_mfma_f32_16x16x32_bf16(af[0][1], b1, acc[0][nn], 0, 0, 0);
            acc[1][nn] = __builtin_amdgcn_mfma_f32_16x16x32_bf16(af[1][0], b0, acc[1][nn], 0, 0, 0);
            acc[1][nn] = __builtin_amdgcn_mfma_f32_16x16x32_bf16(af[1][1], b1, acc[1][nn], 0, 0, 0);
        }
        __syncthreads();
        cur ^= 1;
    }
    #pragma unroll
    for (int mf = 0; mf < 2; mf++)
        #pragma unroll
        for (int nn = 0; nn < 3; nn++){
            int col = (w * 3 + nn) * 16 + lr;
            int row = mf * 16 + lg * 4;
            #pragma unroll
            for (int r = 0; r < 4; r++)
                smem[(row + r) * 200 + col] = bf16one(acc[mf][nn][r]);
        }
    __syncthreads();
    {
        int r2 = tid >> 3, c2 = (tid & 7) * 16;
        const unsigned short* srowp = smem + r2 * 200 + c2;
        unsigned short* dst = (c2 < 64)
            ? kb + (size_t)(b * 2048 + t0 + r2) * 64 + c2
            : qb + (size_t)(b * 2048 + t0 + r2) * 64 + (c2 - 64);
        *(s16x8*)(dst)     = *(const s16x8*)(srowp);
        *(s16x8*)(dst + 8) = *(const s16x8*)(srowp + 8);
        int h = tid >> 2, q3 = tid & 3;
        s16x8 vv;
        #pragma unroll
        for (int e = 0; e < 8; e++)
            vv[e] = smem[(q3 * 8 + e) * 200 + 128 + h];
        *(s16x8*)(vT + (size_t)(b * 64 + h) * 2048 + t0 + q3 * 8) = vv;
    }
}

// ---------------- attn phase A (templated strip count NS): balanced strip jobs ----------------
// grid 8*32*NS: b = bx&7 (XCD-pinned); r = bx>>3: bt = 31 - r/NS (heavy first), strip = r%NS.
// Strip processes chunks c = strip, strip+NS, ... <= bt. strip0 -> raw acc into out;
// strip s>0 -> accp[(s-1)]. Per-row (m,l) -> ml[strip]. Merge kernel combines.
template<int NS>
__global__ __launch_bounds__(256) void attn_part_kernel(const unsigned short* __restrict__ kb,
                                                        const unsigned short* __restrict__ qb,
                                                        const unsigned short* __restrict__ vT,
                                                        float* __restrict__ out,
                                                        float* __restrict__ accp,
                                                        float* __restrict__ ml){
    __shared__ unsigned short Klds[2][64 * 64];
    __shared__ unsigned short Vlds[2][64 * 64];
    int tid = threadIdx.x; int l = tid & 63; int w = tid >> 6;
    int lr = l & 15, lg = l >> 4;
    int bx = blockIdx.x;
    int b = bx & 7;
    int r9 = bx >> 3;
    int bt = 31 - (r9 / NS);
    int strip = r9 % NS;
    int t0 = bt * 64;
    int tw = t0 + w * 16;
    const unsigned short* fqp = kb + (size_t)(b * 2048 + tw + lr) * 64 + lg * 8;
    s16x8 fq0 = *(const s16x8*)(fqp);
    s16x8 fq1 = *(const s16x8*)(fqp + 32);
    const unsigned short* qbb = qb + (size_t)b * 2048 * 64;
    const unsigned short* vbb = vT + (size_t)b * 64 * 2048;

    int srhi = l >> 3;
    int schk = l & 7;
    f32x4 acc[4] = {};
    float mrun = -3.0e38f, lrun = 0.0f;

    // prologue: stage chunk 'strip' into buf 0 (addresses in-bounds even if strip > bt)
    {
        int s0 = strip * 64;
        #pragma unroll
        for (int t = 0; t < 2; t++){
            int ti = w * 2 + t;
            int row = ti * 8 + srhi;
            gload16(qbb + (size_t)(s0 + row) * 64 + ((schk ^ (row & 7)) * 8), &Klds[0][ti * 512]);
            gload16(vbb + (size_t)row * 2048 + s0 + ((schk ^ (row & 7)) * 8), &Vlds[0][ti * 512]);
        }
    }
    __syncthreads();
    int cur = 0;
    for (int c = strip; c <= bt; c += NS){
        int nc = (c + NS <= bt) ? (c + NS) : c;
        int ns0 = nc * 64;
        #pragma unroll
        for (int t = 0; t < 2; t++){
            int ti = w * 2 + t;
            int row = ti * 8 + srhi;
            gload16(qbb + (size_t)(ns0 + row) * 64 + ((schk ^ (row & 7)) * 8), &Klds[cur ^ 1][ti * 512]);
            gload16(vbb + (size_t)row * 2048 + ns0 + ((schk ^ (row & 7)) * 8), &Vlds[cur ^ 1][ti * 512]);
        }
        f32x4 Cs[4];
        #pragma unroll
        for (int n = 0; n < 4; n++){
            int r = n * 16 + lr;
            const unsigned short* ka = &Klds[cur][r * 64];
            s16x8 k0 = *(const s16x8*)(ka + ((lg       ^ (r & 7)) * 8));
            s16x8 k1 = *(const s16x8*)(ka + (((4 + lg) ^ (r & 7)) * 8));
            f32x4 z = {};
            z     = __builtin_amdgcn_mfma_f32_16x16x32_bf16(k0, fq0, z, 0, 0, 0);
            Cs[n] = __builtin_amdgcn_mfma_f32_16x16x32_bf16(k1, fq1, z, 0, 0, 0);
        }
        if (c == bt){
            #pragma unroll
            for (int n = 0; n < 4; n++)
                #pragma unroll
                for (int r = 0; r < 4; r++)
                    if (n * 16 + lg * 4 + r > w * 16 + lr) Cs[n][r] = -3.0e38f;
        }
        float pm = -3.0e38f;
        #pragma unroll
        for (int n = 0; n < 4; n++)
            #pragma unroll
            for (int r = 0; r < 4; r++) pm = fmaxf(pm, Cs[n][r]);
        pm = fmaxf(pm, __shfl_xor(pm, 16));
        pm = fmaxf(pm, __shfl_xor(pm, 32));
        float mnew = fmaxf(mrun, pm);
        float scl = exp2f(mrun - mnew);
        float p[4][4]; float ps = 0.0f;
        #pragma unroll
        for (int n = 0; n < 4; n++)
            #pragma unroll
            for (int r = 0; r < 4; r++){ float e = exp2f(Cs[n][r] - mnew); p[n][r] = e; ps += e; }
        ps += __shfl_xor(ps, 16);
        ps += __shfl_xor(ps, 32);
        lrun = lrun * scl + ps;
        mrun = mnew;
        #pragma unroll
        for (int h16 = 0; h16 < 4; h16++) acc[h16] *= scl;
        s16x4 pb[4];
        #pragma unroll
        for (int n = 0; n < 4; n++){
            u32x2 t; t[0] = bf16pack(p[n][0], p[n][1]); t[1] = bf16pack(p[n][2], p[n][3]);
            pb[n] = __builtin_bit_cast(s16x4, t);
        }
        #pragma unroll
        for (int h16 = 0; h16 < 4; h16++){
            int r = h16 * 16 + lr;
            const unsigned short* va = &Vlds[cur][r * 64];
            #pragma unroll
            for (int sl = 0; sl < 4; sl++){
                s16x4 fv = *(const s16x4*)(va + (((sl * 2 + (lg >> 1)) ^ (r & 7)) * 8) + (lg & 1) * 4);
                acc[h16] = __builtin_amdgcn_mfma_f32_16x16x16bf16_1k(fv, pb[sl], acc[h16], 0, 0, 0);
            }
        }
        __syncthreads();
        cur ^= 1;
    }
    // write raw partial: strip0 -> out, strip s>0 -> accp[s-1]; ml per t-row
    float* accdst = (strip == 0) ? out : (accp + (size_t)(strip - 1) * (8 * 2048 * 64));
    #pragma unroll
    for (int h16 = 0; h16 < 4; h16++)
        *(f32x4*)(accdst + (size_t)(b * 2048 + tw + lr) * 64 + h16 * 16 + lg * 4) = acc[h16];
    if (lg == 0){
        int idx = ((strip * 8 + b) * 32 + bt) * 64 + w * 16 + lr;
        ml[idx * 2]     = mrun;
        ml[idx * 2 + 1] = lrun;
    }
}

// ---------------- attn phase B: merge NS strips per tile ----------------
template<int NS>
__global__ __launch_bounds__(256) void attn_merge_kernel(const float* __restrict__ accp,
                                                         const float* __restrict__ ml,
                                                         float* __restrict__ out){
    int bt = blockIdx.x, b = blockIdx.y;
    int tid = threadIdx.x;
    int row = tid >> 2, cg = (tid & 3) * 16;
    float m[NS], lv[NS];
    float mg = -3.0e38f;
    #pragma unroll
    for (int s = 0; s < NS; s++){
        int idx = (((s * 8 + b) * 32 + bt) * 64 + row) * 2;
        m[s] = ml[idx]; lv[s] = ml[idx + 1];
        mg = fmaxf(mg, m[s]);
    }
    float wt[NS]; float lt = 0.0f;
    #pragma unroll
    for (int s = 0; s < NS; s++){ wt[s] = exp2f(m[s] - mg); lt += lv[s] * wt[s]; }
    float inv = 1.0f / lt;
    size_t base = (size_t)(b * 2048 + bt * 64 + row) * 64 + cg;
    #pragma unroll
    for (int g = 0; g < 4; g++){
        f32x4 o = (*(const f32x4*)(out + base + g * 4)) * wt[0];
        #pragma unroll
        for (int s = 1; s < NS; s++)
            o += (*(const f32x4*)(accp + (size_t)(s - 1) * (8 * 2048 * 64) + base + g * 4)) * wt[s];
        o *= inv;
        *(f32x4*)(out + base + g * 4) = o;
    }
}

// ---------------- Flash attention v8 (fallback if ws too small; passed r8/r9) ----------------
__global__ __launch_bounds__(256) void attn_kernel(const unsigned short* __restrict__ kb,
                                                   const unsigned short* __restrict__ qb,
                                                   const unsigned short* __restrict__ vT,
                                                   float* __restrict__ out){
    __shared__ unsigned short Klds[2][64 * 64];
    __shared__ unsigned short Vlds[2][64 * 64];
    int tid = threadIdx.x; int l = tid & 63; int w = tid >> 6;
    int lr = l & 15, lg = l >> 4;
    int bx = blockIdx.x;
    int b = bx & 7;
    int bt = bx >> 3;
    int t0 = bt * 64;
    int tw = t0 + w * 16;
    const unsigned short* fqp = kb + (size_t)(b * 2048 + tw + lr) * 64 + lg * 8;
    s16x8 fq0 = *(const s16x8*)(fqp);
    s16x8 fq1 = *(const s16x8*)(fqp + 32);
    const unsigned short* qbb = qb + (size_t)b * 2048 * 64;
    const unsigned short* vbb = vT + (size_t)b * 64 * 2048;
    int srhi = l >> 3;
    int schk = l & 7;
    f32x4 acc[4] = {};
    float mrun = -3.0e38f, lrun = 0.0f;
    #pragma unroll
    for (int t = 0; t < 2; t++){
        int ti = w * 2 + t;
        int row = ti * 8 + srhi;
        gload16(qbb + (size_t)row * 64 + ((schk ^ (row & 7)) * 8), &Klds[0][ti * 512]);
        gload16(vbb + (size_t)row * 2048 + ((schk ^ (row & 7)) * 8), &Vlds[0][ti * 512]);
    }
    __syncthreads();
    int cur = 0;
    for (int c = 0; c <= bt; ++c){
        int nc = (c + 1 <= bt) ? (c + 1) : bt;
        int ns0 = nc * 64;
        #pragma unroll
        for (int t = 0; t < 2; t++){
            int ti = w * 2 + t;
            int row = ti * 8 + srhi;
            gload16(qbb + (size_t)(ns0 + row) * 64 + ((schk ^ (row & 7)) * 8), &Klds[cur ^ 1][ti * 512]);
            gload16(vbb + (size_t)row * 2048 + ns0 + ((schk ^ (row & 7)) * 8), &Vlds[cur ^ 1][ti * 512]);
        }
        f32x4 Cs[4];
        #pragma unroll
        for (int n = 0; n < 4; n++){
            int r = n * 16 + lr;
            const unsigned short* ka = &Klds[cur][r * 64];
            s16x8 k0 = *(const s16x8*)(ka + ((lg       ^ (r & 7)) * 8));
            s16x8 k1 = *(const s16x8*)(ka + (((4 + lg) ^ (r & 7)) * 8));
            f32x4 z = {};
            z     = __builtin_amdgcn_mfma_f32_16x16x32_bf16(k0, fq0, z, 0, 0, 0);
            Cs[n] = __builtin_amdgcn_mfma_f32_16x16x32_bf16(k1, fq1, z, 0, 0, 0);
        }
        if (c == bt){
            #pragma unroll
            for (int n = 0; n < 4; n++)
                #pragma unroll
                for (int r = 0; r < 4; r++)
                    if (n * 16 + lg * 4 + r > w * 16 + lr) Cs[n][r] = -3.0e38f;
        }
        float pm = -3.0e38f;
        #pragma unroll
        for (int n = 0; n < 4; n++)
            #pragma unroll
            for (int r = 0; r < 4; r++) pm = fmaxf(pm, Cs[n][r]);
        pm = fmaxf(pm, __shfl_xor(pm, 16));
        pm = fmaxf(pm, __shfl_xor(pm, 32));
        float mnew = fmaxf(mrun, pm);
        float scl = exp2f(mrun - mnew);
        float p[4][4]; float ps = 0.0f;
        #pragma unroll
        for (int n = 0; n < 4; n++)
            #pragma unroll
            for (int r = 0; r < 4; r++){ float e = exp2f(Cs[n][r] - mnew); p[n][r] = e; ps += e; }
        ps += __shfl_xor(ps, 16);
        ps += __shfl_xor(ps, 32);
        lrun = lrun * scl + ps;
        mrun = mnew;
        #pragma unroll
        for (int h16 = 0; h16 < 4; h16++) acc[h16] *= scl;
        s16x4 pb[4];
        #pragma unroll
        for (int n = 0; n < 4; n++){
            u32x2 t; t[0] = bf16pack(p[n][0], p[n][1]); t[1] = bf16pack(p[n][2], p[n][3]);
            pb[n] = __builtin_bit_cast(s16x4, t);
        }
        #pragma unroll
        for (int h16 = 0; h16 < 4; h16++){
            int r = h16 * 16 + lr;
            const unsigned short* va = &Vlds[cur][r * 64];
            #pragma unroll
            for (int sl = 0; sl < 4; sl++){
                s16x4 fv = *(const s16x4*)(va + (((sl * 2 + (lg >> 1)) ^ (r & 7)) * 8) + (lg & 1) * 4);
                acc[h16] = __builtin_amdgcn_mfma_f32_16x16x16bf16_1k(fv, pb[sl], acc[h16], 0, 0, 0);
            }
        }
        __syncthreads();
        cur ^= 1;
    }
    float inv = 1.0f / lrun;
    #pragma unroll
    for (int h16 = 0; h16 < 4; h16++){
        f32x4 o = acc[h16] * inv;
        *(f32x4*)(out + (size_t)(b * 2048 + tw + lr) * 64 + h16 * 16 + lg * 4) = o;
    }
}

extern "C" void kernel_launch(void* const* d_in, const int* in_sizes, int n_in,
                              void* d_out, int out_size, void* d_ws, size_t ws_size,
                              hipStream_t stream) {
    const float* x  = (const float*)d_in[0];
    const float* Wk = (const float*)d_in[1];
    const float* Wq = (const float*)d_in[2];
    const float* Wv = (const float*)d_in[3];
    float* out = (float*)d_out;
    char* ws = (char*)d_ws;
    if (ws_size < (size_t)7 * 1024 * 1024) return;
    unsigned short* WT = (unsigned short*)(ws);              // 384 KB
    unsigned short* kb = (unsigned short*)(ws + (1u << 20)); // 2 MB (k * 0.125*log2e)
    unsigned short* qb = (unsigned short*)(ws + (3u << 20)); // 2 MB
    unsigned short* vT = (unsigned short*)(ws + (5u << 20)); // 2 MB ([b][h][t])
    hipLaunchKernelGGL(wprep_kernel, dim3(3, 8), dim3(256), 0, stream, Wk, Wq, Wv, WT);
    hipLaunchKernelGGL(proj_kernel, dim3(512), dim3(256), 0, stream, x, WT, kb, qb, vT);
    // attn partial buffers: accp = (NS-1) x 4MB at +7MB; ml = NS x 128KB after accp
    if (ws_size >= (size_t)20 * 1024 * 1024){
        float* accp = (float*)(ws + ((size_t)7 << 20));                      // 12 MB (3 arrays)
        float* ml   = (float*)(ws + ((size_t)19 << 20));                     // 512 KB
        hipLaunchKernelGGL((attn_part_kernel<4>), dim3(1024), dim3(256), 0, stream,
                           kb, qb, vT, out, accp, ml);
        hipLaunchKernelGGL((attn_merge_kernel<4>), dim3(32, 8), dim3(256), 0, stream,
                           accp, ml, out);
    } else if (ws_size >= (size_t)12 * 1024 * 1024){
        float* accp = (float*)(ws + ((size_t)7 << 20));                      // 4 MB (1 array)
        float* ml   = (float*)(ws + ((size_t)11 << 20));                     // 256 KB
        hipLaunchKernelGGL((attn_part_kernel<2>), dim3(512), dim3(256), 0, stream,
                           kb, qb, vT, out, accp, ml);
        hipLaunchKernelGGL((attn_merge_kernel<2>), dim3(32, 8), dim3(256), 0, stream,
                           accp, ml, out);
    } else {
        hipLaunchKernelGGL(attn_kernel, dim3(256), dim3(256), 0, stream, kb, qb, vT, out);
    }
}